// Round 11
// baseline (591.220 us; speedup 1.0000x reference)
//
#include <hip/hip_runtime.h>
#include <hip/hip_bf16.h>

#define NN 100000
#define NE 1600000
#define FIN 32
#define FH 16
#define NG 256
#define EPS 1e-5f
#define ABLK 8192                      // edges per binning block
#define NAB ((NE + ABLK - 1) / ABLK)   // 196 binning blocks
#define BKN 128                        // nodes per bucket
#define NBUK ((NN + BKN - 1) / BKN)    // 782 buckets

// ---------------------------------------------------------------------------
// countA: per-(bucket,block) edge counts. LDS histogram over 782 buckets,
// then dense writes to cntmat[bucket][block]. No global atomics.
// (round-6 lesson: scatter's 4B random stores -> 105MB HBM write-through,
//  16x amplification. This design keeps all bulk writes line-dense.)
// ---------------------------------------------------------------------------
__global__ __launch_bounds__(256) void countA_kernel(const int* __restrict__ ei,
                                                     int* __restrict__ cntmat) {
  __shared__ int cnt[NBUK];
  int t = threadIdx.x, blk = blockIdx.x;
  for (int i = t; i < NBUK; i += 256) cnt[i] = 0;
  __syncthreads();
  int e0 = blk * ABLK;
  for (int i = 0; i < ABLK / 256; i++) {
    int e = e0 + t + i * 256;
    if (e < NE) atomicAdd(&cnt[ei[NE + e] >> 7], 1);
  }
  __syncthreads();
  for (int i = t; i < NBUK; i += 256) cntmat[i * NAB + blk] = cnt[i];
}

// ---------------------------------------------------------------------------
// bscan1: bucket totals (one thread per bucket, contiguous row reads).
// ---------------------------------------------------------------------------
__global__ __launch_bounds__(256) void bscan1_kernel(const int* __restrict__ cntmat,
                                                     int* __restrict__ bucket_cnt) {
  int b = blockIdx.x * 256 + threadIdx.x;
  if (b >= NBUK) return;
  const int* row = cntmat + b * NAB;
  int s = 0;
  for (int k = 0; k < NAB; k++) s += row[k];
  bucket_cnt[b] = s;
}

// ---------------------------------------------------------------------------
// bscan2: exclusive scan of 782 bucket totals -> bucket_base[783].
// ---------------------------------------------------------------------------
__global__ __launch_bounds__(1024) void bscan2_kernel(const int* __restrict__ bucket_cnt,
                                                      int* __restrict__ bucket_base) {
  __shared__ int part[1024];
  int t = threadIdx.x;
  int v = (t < NBUK) ? bucket_cnt[t] : 0;
  part[t] = v;
  __syncthreads();
  for (int off = 1; off < 1024; off <<= 1) {
    int u = (t >= off) ? part[t - off] : 0;
    __syncthreads();
    part[t] += u;
    __syncthreads();
  }
  if (t < NBUK) bucket_base[t] = part[t] - v;
  if (t == 1023) bucket_base[NBUK] = part[1023];
}

// ---------------------------------------------------------------------------
// bscan3: per-(bucket,block) base offsets, in place on cntmat.
// ---------------------------------------------------------------------------
__global__ __launch_bounds__(256) void bscan3_kernel(int* __restrict__ cntmat,
                                                     const int* __restrict__ bucket_base) {
  int b = blockIdx.x * 256 + threadIdx.x;
  if (b >= NBUK) return;
  int acc = bucket_base[b];
  int* row = cntmat + b * NAB;
  for (int k = 0; k < NAB; k++) {
    int c = row[k];
    row[k] = acc;
    acc += c;
  }
}

// ---------------------------------------------------------------------------
// binB: write edges into bucket-grouped layout. Each (block,bucket) range is
// exclusively owned -> LDS rank counter, no global atomics. Payload packed
// to one u32: src(17b) | dst_local(7b)<<17.
// ---------------------------------------------------------------------------
__global__ __launch_bounds__(256) void binB_kernel(const int* __restrict__ ei,
                                                   const int* __restrict__ blockbase,
                                                   unsigned int* __restrict__ binned) {
  __shared__ int base[NBUK];
  __shared__ int cnt2[NBUK];
  int t = threadIdx.x, blk = blockIdx.x;
  for (int i = t; i < NBUK; i += 256) {
    base[i] = blockbase[i * NAB + blk];
    cnt2[i] = 0;
  }
  __syncthreads();
  int e0 = blk * ABLK;
  for (int i = 0; i < ABLK / 256; i++) {
    int e = e0 + t + i * 256;
    if (e < NE) {
      int src = ei[e];
      int dst = ei[NE + e];
      int bk = dst >> 7;
      int r = atomicAdd(&cnt2[bk], 1);
      binned[base[bk] + r] = (unsigned)src | ((unsigned)(dst & 127) << 17);
    }
  }
}

// ---------------------------------------------------------------------------
// proj1: y1 = x @ W1l.T, r1 = x @ W1r.T (projection BEFORE aggregation:
// linear map commutes with segment_sum; gathers run in 16-dim space).
// ---------------------------------------------------------------------------
__global__ __launch_bounds__(256) void proj1_kernel(
    const float* __restrict__ x,
    const float* __restrict__ W1l, const float* __restrict__ W1r,
    float* __restrict__ y1, float* __restrict__ r1) {
  __shared__ float sWl[FH * FIN];
  __shared__ float sWr[FH * FIN];
  int t = threadIdx.x;
  for (int i = t; i < FH * FIN; i += 256) {
    sWl[i] = W1l[i];
    sWr[i] = W1r[i];
  }
  __syncthreads();

  int n = blockIdx.x * 256 + t;
  if (n >= NN) return;
  float xl[FIN];
#pragma unroll
  for (int k = 0; k < FIN; k += 4) {
    float4 v = *(const float4*)(x + n * FIN + k);
    xl[k] = v.x; xl[k + 1] = v.y; xl[k + 2] = v.z; xl[k + 3] = v.w;
  }
  float yo[FH], ro[FH];
#pragma unroll
  for (int j = 0; j < FH; j++) {
    float a = 0.f, b = 0.f;
#pragma unroll
    for (int k = 0; k < FIN; k++) {
      a += sWl[j * FIN + k] * xl[k];
      b += sWr[j * FIN + k] * xl[k];
    }
    yo[j] = a; ro[j] = b;
  }
#pragma unroll
  for (int j = 0; j < FH; j += 4) {
    *(float4*)(y1 + n * FH + j) = make_float4(yo[j], yo[j + 1], yo[j + 2], yo[j + 3]);
    *(float4*)(r1 + n * FH + j) = make_float4(ro[j], ro[j + 1], ro[j + 2], ro[j + 3]);
  }
}

// ---------------------------------------------------------------------------
// aggC1: one bucket per block. Coalesced binned-edge reads; random y1[src]
// gathers; LDS f32 accumulation (zero global f32 atomics). Fused conv1
// epilogue: h1 = relu(acc/deg + r1 + b1), invd saved, BN-stats partials.
// ---------------------------------------------------------------------------
__global__ __launch_bounds__(256) void aggC1_kernel(
    const unsigned int* __restrict__ binned, const int* __restrict__ bucket_base,
    const float* __restrict__ y1, const float* __restrict__ r1,
    const float* __restrict__ b1,
    float* __restrict__ h1, float* __restrict__ invd_out,
    float* __restrict__ partials) {
  __shared__ float acc[BKN][FH];
  __shared__ int cnt[BKN];
  __shared__ float sstat[4][32];
  int t = threadIdx.x, b = blockIdx.x;
  float* af = &acc[0][0];
  for (int i = t; i < BKN * FH; i += 256) af[i] = 0.f;
  for (int i = t; i < BKN; i += 256) cnt[i] = 0;
  __syncthreads();

  int ebeg = bucket_base[b], eend = bucket_base[b + 1];
  int c = t & 3;
  for (int e = ebeg + (t >> 2); e < eend; e += 64) {
    unsigned v = binned[e];
    int src = v & 0x1FFFF;
    int dl = (v >> 17) & 127;
    float4 g = *(const float4*)(y1 + src * FH + c * 4);
    atomicAdd(&acc[dl][c * 4 + 0], g.x);
    atomicAdd(&acc[dl][c * 4 + 1], g.y);
    atomicAdd(&acc[dl][c * 4 + 2], g.z);
    atomicAdd(&acc[dl][c * 4 + 3], g.w);
    if (c == 0) atomicAdd(&cnt[dl], 1);
  }
  __syncthreads();

  // finish conv1 for this bucket's 128 nodes: 2 threads/node, 8 ch each
  int nl = t >> 1, half = t & 1;
  int gnode = b * BKN + nl;
  float h[8];
  if (gnode < NN) {
    float ivd = 1.0f / (float)max(cnt[nl], 1);
    float4 rv0 = *(const float4*)(r1 + gnode * FH + half * 8);
    float4 rv1 = *(const float4*)(r1 + gnode * FH + half * 8 + 4);
    float rr[8] = {rv0.x, rv0.y, rv0.z, rv0.w, rv1.x, rv1.y, rv1.z, rv1.w};
#pragma unroll
    for (int k = 0; k < 8; k++) {
      int ch = half * 8 + k;
      h[k] = fmaxf(acc[nl][ch] * ivd + rr[k] + b1[ch], 0.f);
    }
    *(float4*)(h1 + gnode * FH + half * 8) = make_float4(h[0], h[1], h[2], h[3]);
    *(float4*)(h1 + gnode * FH + half * 8 + 4) = make_float4(h[4], h[5], h[6], h[7]);
    if (half == 0) invd_out[gnode] = ivd;
  } else {
#pragma unroll
    for (int k = 0; k < 8; k++) h[k] = 0.f;
  }

  // per-channel s,q over the wave's 32 nodes (parity-preserving shuffles)
  float s[8], q[8];
#pragma unroll
  for (int k = 0; k < 8; k++) { s[k] = h[k]; q[k] = h[k] * h[k]; }
#pragma unroll
  for (int off = 2; off < 64; off <<= 1) {
#pragma unroll
    for (int k = 0; k < 8; k++) {
      s[k] += __shfl_xor(s[k], off);
      q[k] += __shfl_xor(q[k], off);
    }
  }
  int t6 = t & 63, w = t >> 6;
  if (t6 < 2) {
#pragma unroll
    for (int k = 0; k < 8; k++) {
      sstat[w][t6 * 8 + k] = s[k];        // ch = half*8+k, half==t6
      sstat[w][16 + t6 * 8 + k] = q[k];
    }
  }
  __syncthreads();
  if (t < 32)
    partials[b * 32 + t] = sstat[0][t] + sstat[1][t] + sstat[2][t] + sstat[3][t];
}

// ---------------------------------------------------------------------------
// bn1_params: reduce per-block partials then finalize BN1 scale/shift.
// ---------------------------------------------------------------------------
__global__ __launch_bounds__(1024) void bn1_params_kernel(
    const float* __restrict__ partials, int P,
    const float* __restrict__ g1, const float* __restrict__ be1,
    float* __restrict__ scsh) {
  __shared__ float red[32][33];
  __shared__ float tot[32];
  int t = threadIdx.x;
  int ch = t & 31, seg = t >> 5;
  float s = 0.f;
  for (int b = seg; b < P; b += 32) s += partials[b * 32 + ch];
  red[seg][ch] = s;
  __syncthreads();
  if (t < 32) {
    float v = 0.f;
    for (int k = 0; k < 32; k++) v += red[k][t];
    tot[t] = v;
  }
  __syncthreads();
  if (t < FH) {
    float m = tot[t] * (1.0f / NN);
    float var = tot[FH + t] * (1.0f / NN) - m * m;
    float sc = g1[t] * rsqrtf(var + EPS);
    scsh[t] = sc;
    scsh[FH + t] = be1[t] - m * sc;
  }
}

// ---------------------------------------------------------------------------
// proj2: hb = bn1(h1) on the fly, p2 = hb @ W2l.T, r2 = hb @ W2r.T.
// ---------------------------------------------------------------------------
__global__ __launch_bounds__(256) void proj2_kernel(
    const float* __restrict__ h1, const float* __restrict__ scsh,
    const float* __restrict__ W2l, const float* __restrict__ W2r,
    float* __restrict__ p2, float* __restrict__ r2) {
  __shared__ float sWl[FH * FH];
  __shared__ float sWr[FH * FH];
  __shared__ float sc[FH], sh[FH];
  int t = threadIdx.x;
  if (t < FH * FH) {
    sWl[t] = W2l[t];
    sWr[t] = W2r[t];
  }
  if (t < FH) {
    sc[t] = scsh[t];
    sh[t] = scsh[FH + t];
  }
  __syncthreads();

  int n = blockIdx.x * 256 + t;
  if (n >= NN) return;
  float hb[FH];
#pragma unroll
  for (int k = 0; k < FH; k += 4) {
    float4 v = *(const float4*)(h1 + n * FH + k);
    hb[k]     = v.x * sc[k]     + sh[k];
    hb[k + 1] = v.y * sc[k + 1] + sh[k + 1];
    hb[k + 2] = v.z * sc[k + 2] + sh[k + 2];
    hb[k + 3] = v.w * sc[k + 3] + sh[k + 3];
  }
  float po[FH], ro[FH];
#pragma unroll
  for (int j = 0; j < FH; j++) {
    float a = 0.f, b = 0.f;
#pragma unroll
    for (int k = 0; k < FH; k++) {
      a += sWl[j * FH + k] * hb[k];
      b += sWr[j * FH + k] * hb[k];
    }
    po[j] = a; ro[j] = b;
  }
#pragma unroll
  for (int j = 0; j < FH; j += 4) {
    *(float4*)(p2 + n * FH + j) = make_float4(po[j], po[j + 1], po[j + 2], po[j + 3]);
    *(float4*)(r2 + n * FH + j) = make_float4(ro[j], ro[j + 1], ro[j + 2], ro[j + 3]);
  }
}

// ---------------------------------------------------------------------------
// aggC2: same bucket aggregation for conv2 + fused graph mean-pool.
// Bucket = contiguous node range -> spans <=2 graphs typically; LDS gpool,
// then a few global atomics per block (spread over 256 lines).
// ---------------------------------------------------------------------------
__global__ __launch_bounds__(256) void aggC2_kernel(
    const unsigned int* __restrict__ binned, const int* __restrict__ bucket_base,
    const float* __restrict__ p2, const float* __restrict__ r2,
    const float* __restrict__ b2, const float* __restrict__ invd,
    const int* __restrict__ batch, float* __restrict__ gsum) {
  __shared__ float acc[BKN][FH];
  __shared__ float gpool[8][FH];
  __shared__ int g0s, smaxs;
  int t = threadIdx.x, b = blockIdx.x;
  float* af = &acc[0][0];
  for (int i = t; i < BKN * FH; i += 256) af[i] = 0.f;
  for (int i = t; i < 8 * FH; i += 256) (&gpool[0][0])[i] = 0.f;
  if (t == 0) {
    g0s = batch[b * BKN];
    smaxs = batch[min(b * BKN + BKN - 1, NN - 1)] - batch[b * BKN];
  }
  __syncthreads();

  int ebeg = bucket_base[b], eend = bucket_base[b + 1];
  int c = t & 3;
  for (int e = ebeg + (t >> 2); e < eend; e += 64) {
    unsigned v = binned[e];
    int src = v & 0x1FFFF;
    int dl = (v >> 17) & 127;
    float4 g = *(const float4*)(p2 + src * FH + c * 4);
    atomicAdd(&acc[dl][c * 4 + 0], g.x);
    atomicAdd(&acc[dl][c * 4 + 1], g.y);
    atomicAdd(&acc[dl][c * 4 + 2], g.z);
    atomicAdd(&acc[dl][c * 4 + 3], g.w);
  }
  __syncthreads();

  int nl = t >> 1, half = t & 1;
  int gnode = b * BKN + nl;
  if (gnode < NN) {
    float ivd = invd[gnode];
    float4 rv0 = *(const float4*)(r2 + gnode * FH + half * 8);
    float4 rv1 = *(const float4*)(r2 + gnode * FH + half * 8 + 4);
    float rr[8] = {rv0.x, rv0.y, rv0.z, rv0.w, rv1.x, rv1.y, rv1.z, rv1.w};
    int slot = batch[gnode] - g0s;
#pragma unroll
    for (int k = 0; k < 8; k++) {
      int ch = half * 8 + k;
      float hv = fmaxf(acc[nl][ch] * ivd + rr[k] + b2[ch], 0.f);
      if (slot < 8)
        atomicAdd(&gpool[slot][ch], hv);
      else
        atomicAdd(gsum + (g0s + slot) * FH + ch, hv);  // rare spill path
    }
  }
  __syncthreads();

  int nslots = smaxs + 1;
  if (t < nslots * FH && t < 8 * FH) {
    int s = t >> 4, ch = t & 15;
    atomicAdd(gsum + (g0s + s) * FH + ch, gpool[s][ch]);
  }
}

// ---------------------------------------------------------------------------
// head: whole D2RL dense head in one block; per-graph counts via binary
// search on sorted batch.
// ---------------------------------------------------------------------------
__global__ __launch_bounds__(256) void head_kernel(
    const float* __restrict__ gsum, const int* __restrict__ batch,
    const float* __restrict__ gn1, const float* __restrict__ bn1,
    const float* __restrict__ Wl1, const float* __restrict__ bl1,
    const float* __restrict__ gn2, const float* __restrict__ bn2,
    const float* __restrict__ Wl2, const float* __restrict__ bl2,
    const float* __restrict__ gn3, const float* __restrict__ bn3,
    const float* __restrict__ Wl3, const float* __restrict__ bl3,
    const float* __restrict__ Wout, const float* __restrict__ bout,
    float* __restrict__ out) {
  __shared__ float sxe[FH * NG];
  __shared__ float sz[FH * NG];
  __shared__ float sz2[FH * NG];
  __shared__ float sc1[FH], sh1[FH], sc2[2 * FH], sh2[2 * FH], sc3[2 * FH], sh3[2 * FH];

  int g = threadIdx.x;
  int lo = 0, hi = NN;
  while (lo < hi) { int mid = (lo + hi) >> 1; if (batch[mid] < g) lo = mid + 1; else hi = mid; }
  int lo2 = lo, hi2 = NN;
  while (lo2 < hi2) { int mid = (lo2 + hi2) >> 1; if (batch[mid] < g + 1) lo2 = mid + 1; else hi2 = mid; }
  float cnt = fmaxf((float)(lo2 - lo), 1.0f);

  float xe[FH];
#pragma unroll
  for (int c = 0; c < FH; c++) {
    xe[c] = gsum[g * FH + c] / cnt;
    sxe[c * NG + g] = xe[c];
  }
  __syncthreads();

  if (g < FH) {
    float s = 0.f, q = 0.f;
    for (int i = 0; i < NG; i++) {
      float v = sxe[g * NG + i];
      s += v; q += v * v;
    }
    float m = s * (1.0f / NG);
    float var = q * (1.0f / NG) - m * m;
    float sc = gn1[g] * rsqrtf(var + EPS);
    sc1[g] = sc;
    sh1[g] = bn1[g] - m * sc;
  }
  __syncthreads();

  float z1[FH];
  {
    float xb[FH];
#pragma unroll
    for (int k = 0; k < FH; k++) xb[k] = xe[k] * sc1[k] + sh1[k];
#pragma unroll
    for (int j = 0; j < FH; j++) {
      float acc = bl1[j];
#pragma unroll
      for (int k = 0; k < FH; k++) acc += Wl1[j * FH + k] * xb[k];
      z1[j] = fmaxf(acc, 0.f);
      sz[j * NG + g] = z1[j];
    }
  }
  __syncthreads();

  if (g < 2 * FH) {
    const float* col = (g < FH) ? (sz + g * NG) : (sxe + (g - FH) * NG);
    float s = 0.f, q = 0.f;
    for (int i = 0; i < NG; i++) {
      float v = col[i];
      s += v; q += v * v;
    }
    float m = s * (1.0f / NG);
    float var = q * (1.0f / NG) - m * m;
    float sc = gn2[g] * rsqrtf(var + EPS);
    sc2[g] = sc;
    sh2[g] = bn2[g] - m * sc;
  }
  __syncthreads();

  float z2[FH];
  {
    float cat[2 * FH];
#pragma unroll
    for (int k = 0; k < FH; k++) {
      cat[k] = z1[k] * sc2[k] + sh2[k];
      cat[FH + k] = xe[k] * sc2[FH + k] + sh2[FH + k];
    }
#pragma unroll
    for (int j = 0; j < FH; j++) {
      float acc = bl2[j];
#pragma unroll
      for (int k = 0; k < 2 * FH; k++) acc += Wl2[j * 2 * FH + k] * cat[k];
      z2[j] = fmaxf(acc, 0.f);
      sz2[j * NG + g] = z2[j];
    }
  }
  __syncthreads();

  if (g < 2 * FH) {
    const float* col = (g < FH) ? (sz2 + g * NG) : (sxe + (g - FH) * NG);
    float s = 0.f, q = 0.f;
    for (int i = 0; i < NG; i++) {
      float v = col[i];
      s += v; q += v * v;
    }
    float m = s * (1.0f / NG);
    float var = q * (1.0f / NG) - m * m;
    float sc = gn3[g] * rsqrtf(var + EPS);
    sc3[g] = sc;
    sh3[g] = bn3[g] - m * sc;
  }
  __syncthreads();

  {
    float cat[2 * FH];
#pragma unroll
    for (int k = 0; k < FH; k++) {
      cat[k] = z2[k] * sc3[k] + sh3[k];
      cat[FH + k] = xe[k] * sc3[FH + k] + sh3[FH + k];
    }
    float o = bout[0];
#pragma unroll
    for (int j = 0; j < FH; j++) {
      float acc = bl3[j];
#pragma unroll
      for (int k = 0; k < 2 * FH; k++) acc += Wl3[j * 2 * FH + k] * cat[k];
      o += Wout[j] * fmaxf(acc, 0.f);
    }
    out[g] = o;
  }
}

// ---------------------------------------------------------------------------
extern "C" void kernel_launch(void* const* d_in, const int* in_sizes, int n_in,
                              void* d_out, int out_size, void* d_ws, size_t ws_size,
                              hipStream_t stream) {
  const float* x    = (const float*)d_in[0];
  const int*   ei   = (const int*)d_in[1];
  const int*   batch= (const int*)d_in[2];
  const float* W1l  = (const float*)d_in[3];
  const float* W1r  = (const float*)d_in[4];
  const float* b1   = (const float*)d_in[5];
  const float* g1   = (const float*)d_in[6];
  const float* be1  = (const float*)d_in[7];
  const float* W2l  = (const float*)d_in[8];
  const float* W2r  = (const float*)d_in[9];
  const float* b2   = (const float*)d_in[10];
  const float* gn1  = (const float*)d_in[11];
  const float* bn1  = (const float*)d_in[12];
  const float* Wl1  = (const float*)d_in[13];
  const float* bl1  = (const float*)d_in[14];
  const float* gn2  = (const float*)d_in[15];
  const float* bn2  = (const float*)d_in[16];
  const float* Wl2  = (const float*)d_in[17];
  const float* bl2  = (const float*)d_in[18];
  const float* gn3  = (const float*)d_in[19];
  const float* bn3  = (const float*)d_in[20];
  const float* Wl3  = (const float*)d_in[21];
  const float* bl3  = (const float*)d_in[22];
  const float* Wout = (const float*)d_in[23];
  const float* bout = (const float*)d_in[24];

  int* wi = (int*)d_ws;
  // zeroed region (one 16KB memset):
  float* gsum        = (float*)wi;                      // [NG*FH] = 4096
  // non-zeroed:
  int*   cntmat      = wi + NG * FH;                    // [NBUK*NAB] -> blockbase after bscan3
  int*   bucket_cnt  = cntmat + NBUK * NAB;             // [NBUK]
  int*   bucket_base = bucket_cnt + NBUK;               // [NBUK+1]
  unsigned int* binned = (unsigned int*)(bucket_base + NBUK + 1);  // [NE]
  float* invd        = (float*)(binned + NE);           // [NN]
  float* partials    = invd + NN;                       // [NBUK*32]
  float* scsh        = partials + NBUK * 32;            // [32]
  float* y1          = scsh + 32;                       // [NN*16] (reused as p2)
  float* r1          = y1 + (size_t)NN * FH;            // [NN*16] (reused as r2)
  float* h1          = r1 + (size_t)NN * FH;            // [NN*16]
  float* p2          = y1;
  float* r2          = r1;

  hipMemsetAsync(d_ws, 0, (size_t)NG * FH * sizeof(float), stream);

  int nodeBlocks = (NN + 255) / 256;

  countA_kernel<<<NAB, 256, 0, stream>>>(ei, cntmat);
  bscan1_kernel<<<(NBUK + 255) / 256, 256, 0, stream>>>(cntmat, bucket_cnt);
  bscan2_kernel<<<1, 1024, 0, stream>>>(bucket_cnt, bucket_base);
  bscan3_kernel<<<(NBUK + 255) / 256, 256, 0, stream>>>(cntmat, bucket_base);
  binB_kernel<<<NAB, 256, 0, stream>>>(ei, cntmat, binned);
  proj1_kernel<<<nodeBlocks, 256, 0, stream>>>(x, W1l, W1r, y1, r1);
  aggC1_kernel<<<NBUK, 256, 0, stream>>>(binned, bucket_base, y1, r1, b1, h1, invd, partials);
  bn1_params_kernel<<<1, 1024, 0, stream>>>(partials, NBUK, g1, be1, scsh);
  proj2_kernel<<<nodeBlocks, 256, 0, stream>>>(h1, scsh, W2l, W2r, p2, r2);
  aggC2_kernel<<<NBUK, 256, 0, stream>>>(binned, bucket_base, p2, r2, b2, invd, batch, gsum);
  head_kernel<<<1, 256, 0, stream>>>(gsum, batch, gn1, bn1, Wl1, bl1,
                                     gn2, bn2, Wl2, bl2, gn3, bn3, Wl3, bl3,
                                     Wout, bout, (float*)d_out);
}

// Round 12
// 568.521 us; speedup vs baseline: 1.0399x; 1.0399x over previous
//
#include <hip/hip_runtime.h>
#include <hip/hip_bf16.h>

#define NN 100000
#define NE 1600000
#define FIN 32
#define FH 16
#define NG 256
#define EPS 1e-5f
#define ABLK 8192                      // edges per binning block
#define NAB ((NE + ABLK - 1) / ABLK)   // 196 binning blocks
#define BKN 64                         // nodes per bucket (r11: 128 -> 21% occ; 64 doubles grid)
#define BSH 6                          // log2(BKN)
#define NBUK ((NN + BKN - 1) / BKN)    // 1563 buckets

// ---------------------------------------------------------------------------
// countA: per-(bucket,block) edge counts. LDS histogram, dense writes.
// ---------------------------------------------------------------------------
__global__ __launch_bounds__(256) void countA_kernel(const int* __restrict__ ei,
                                                     int* __restrict__ cntmat) {
  __shared__ int cnt[NBUK];
  int t = threadIdx.x, blk = blockIdx.x;
  for (int i = t; i < NBUK; i += 256) cnt[i] = 0;
  __syncthreads();
  int e0 = blk * ABLK;
  for (int i = 0; i < ABLK / 256; i++) {
    int e = e0 + t + i * 256;
    if (e < NE) atomicAdd(&cnt[ei[NE + e] >> BSH], 1);
  }
  __syncthreads();
  for (int i = t; i < NBUK; i += 256) cntmat[i * NAB + blk] = cnt[i];
}

// ---------------------------------------------------------------------------
// bscan1: bucket totals (one thread per bucket, contiguous row reads).
// ---------------------------------------------------------------------------
__global__ __launch_bounds__(256) void bscan1_kernel(const int* __restrict__ cntmat,
                                                     int* __restrict__ bucket_cnt) {
  int b = blockIdx.x * 256 + threadIdx.x;
  if (b >= NBUK) return;
  const int* row = cntmat + b * NAB;
  int s = 0;
  for (int k = 0; k < NAB; k++) s += row[k];
  bucket_cnt[b] = s;
}

// ---------------------------------------------------------------------------
// bscan2: exclusive scan of NBUK(=1563) totals, 2 buckets/thread.
// ---------------------------------------------------------------------------
__global__ __launch_bounds__(1024) void bscan2_kernel(const int* __restrict__ bucket_cnt,
                                                      int* __restrict__ bucket_base) {
  __shared__ int part[1024];
  int t = threadIdx.x;
  int i0 = 2 * t;
  int d0 = (i0 < NBUK) ? bucket_cnt[i0] : 0;
  int d1 = (i0 + 1 < NBUK) ? bucket_cnt[i0 + 1] : 0;
  int ts = d0 + d1;
  part[t] = ts;
  __syncthreads();
  for (int off = 1; off < 1024; off <<= 1) {
    int u = (t >= off) ? part[t - off] : 0;
    __syncthreads();
    part[t] += u;
    __syncthreads();
  }
  int base = part[t] - ts;
  if (i0 < NBUK) bucket_base[i0] = base;
  if (i0 + 1 < NBUK) bucket_base[i0 + 1] = base + d0;
  if (t == 1023) bucket_base[NBUK] = part[1023];
}

// ---------------------------------------------------------------------------
// bscan3: per-(bucket,block) base offsets, in place on cntmat.
// ---------------------------------------------------------------------------
__global__ __launch_bounds__(256) void bscan3_kernel(int* __restrict__ cntmat,
                                                     const int* __restrict__ bucket_base) {
  int b = blockIdx.x * 256 + threadIdx.x;
  if (b >= NBUK) return;
  int acc = bucket_base[b];
  int* row = cntmat + b * NAB;
  for (int k = 0; k < NAB; k++) {
    int c = row[k];
    row[k] = acc;
    acc += c;
  }
}

// ---------------------------------------------------------------------------
// binB: write edges bucket-grouped; per-(block,bucket) ranges exclusively
// owned -> LDS rank counters, no global atomics. u32 payload:
// src(17b) | dst_local(6b)<<17.
// ---------------------------------------------------------------------------
__global__ __launch_bounds__(256) void binB_kernel(const int* __restrict__ ei,
                                                   const int* __restrict__ blockbase,
                                                   unsigned int* __restrict__ binned) {
  __shared__ int base[NBUK];
  __shared__ int cnt2[NBUK];
  int t = threadIdx.x, blk = blockIdx.x;
  for (int i = t; i < NBUK; i += 256) {
    base[i] = blockbase[i * NAB + blk];
    cnt2[i] = 0;
  }
  __syncthreads();
  int e0 = blk * ABLK;
  for (int i = 0; i < ABLK / 256; i++) {
    int e = e0 + t + i * 256;
    if (e < NE) {
      int src = ei[e];
      int dst = ei[NE + e];
      int bk = dst >> BSH;
      int r = atomicAdd(&cnt2[bk], 1);
      binned[base[bk] + r] = (unsigned)src | ((unsigned)(dst & (BKN - 1)) << 17);
    }
  }
}

// ---------------------------------------------------------------------------
// proj1: y1 = x @ W1l.T, r1 = x @ W1r.T (projection BEFORE aggregation).
// ---------------------------------------------------------------------------
__global__ __launch_bounds__(256) void proj1_kernel(
    const float* __restrict__ x,
    const float* __restrict__ W1l, const float* __restrict__ W1r,
    float* __restrict__ y1, float* __restrict__ r1) {
  __shared__ float sWl[FH * FIN];
  __shared__ float sWr[FH * FIN];
  int t = threadIdx.x;
  for (int i = t; i < FH * FIN; i += 256) {
    sWl[i] = W1l[i];
    sWr[i] = W1r[i];
  }
  __syncthreads();

  int n = blockIdx.x * 256 + t;
  if (n >= NN) return;
  float xl[FIN];
#pragma unroll
  for (int k = 0; k < FIN; k += 4) {
    float4 v = *(const float4*)(x + n * FIN + k);
    xl[k] = v.x; xl[k + 1] = v.y; xl[k + 2] = v.z; xl[k + 3] = v.w;
  }
  float yo[FH], ro[FH];
#pragma unroll
  for (int j = 0; j < FH; j++) {
    float a = 0.f, b = 0.f;
#pragma unroll
    for (int k = 0; k < FIN; k++) {
      a += sWl[j * FIN + k] * xl[k];
      b += sWr[j * FIN + k] * xl[k];
    }
    yo[j] = a; ro[j] = b;
  }
#pragma unroll
  for (int j = 0; j < FH; j += 4) {
    *(float4*)(y1 + n * FH + j) = make_float4(yo[j], yo[j + 1], yo[j + 2], yo[j + 3]);
    *(float4*)(r1 + n * FH + j) = make_float4(ro[j], ro[j + 1], ro[j + 2], ro[j + 3]);
  }
}

// ---------------------------------------------------------------------------
// aggC1: one 64-node bucket per block; unroll-2 edge loop (2 independent
// gathers in flight per lane -- r11 lesson: MLP + occupancy, not bandwidth,
// bound this kernel). acc padded FH+1 to spread LDS banks. Fused conv1
// epilogue (4 thr/node): relu(acc/deg + r1 + b1), invd saved, BN partials.
// ---------------------------------------------------------------------------
__global__ __launch_bounds__(256) void aggC1_kernel(
    const unsigned int* __restrict__ binned, const int* __restrict__ bucket_base,
    const float* __restrict__ y1, const float* __restrict__ r1,
    const float* __restrict__ b1,
    float* __restrict__ h1, float* __restrict__ invd_out,
    float* __restrict__ partials) {
  __shared__ float acc[BKN][FH + 1];
  __shared__ int cnt[BKN];
  __shared__ float sstat[4][32];
  int t = threadIdx.x, b = blockIdx.x;
  float* af = &acc[0][0];
  for (int i = t; i < BKN * (FH + 1); i += 256) af[i] = 0.f;
  if (t < BKN) cnt[t] = 0;
  __syncthreads();

  int ebeg = bucket_base[b], eend = bucket_base[b + 1];
  int c = t & 3;
  int e = ebeg + (t >> 2);
  for (; e + 64 < eend; e += 128) {
    unsigned v0 = binned[e];
    unsigned v1 = binned[e + 64];
    int s0 = v0 & 0x1FFFF, d0 = (v0 >> 17) & (BKN - 1);
    int s1 = v1 & 0x1FFFF, d1 = (v1 >> 17) & (BKN - 1);
    float4 g0 = *(const float4*)(y1 + s0 * FH + c * 4);
    float4 g1 = *(const float4*)(y1 + s1 * FH + c * 4);
    atomicAdd(&acc[d0][c * 4 + 0], g0.x);
    atomicAdd(&acc[d0][c * 4 + 1], g0.y);
    atomicAdd(&acc[d0][c * 4 + 2], g0.z);
    atomicAdd(&acc[d0][c * 4 + 3], g0.w);
    atomicAdd(&acc[d1][c * 4 + 0], g1.x);
    atomicAdd(&acc[d1][c * 4 + 1], g1.y);
    atomicAdd(&acc[d1][c * 4 + 2], g1.z);
    atomicAdd(&acc[d1][c * 4 + 3], g1.w);
    if (c == 0) {
      atomicAdd(&cnt[d0], 1);
      atomicAdd(&cnt[d1], 1);
    }
  }
  if (e < eend) {
    unsigned v0 = binned[e];
    int s0 = v0 & 0x1FFFF, d0 = (v0 >> 17) & (BKN - 1);
    float4 g0 = *(const float4*)(y1 + s0 * FH + c * 4);
    atomicAdd(&acc[d0][c * 4 + 0], g0.x);
    atomicAdd(&acc[d0][c * 4 + 1], g0.y);
    atomicAdd(&acc[d0][c * 4 + 2], g0.z);
    atomicAdd(&acc[d0][c * 4 + 3], g0.w);
    if (c == 0) atomicAdd(&cnt[d0], 1);
  }
  __syncthreads();

  // conv1 epilogue: 4 threads/node, 4 channels each
  int nl = t >> 2, q = t & 3;
  int gnode = b * BKN + nl;
  float h[4];
  if (gnode < NN) {
    float ivd = 1.0f / (float)max(cnt[nl], 1);
    float4 rv = *(const float4*)(r1 + gnode * FH + q * 4);
    float4 bv = *(const float4*)(b1 + q * 4);
    h[0] = fmaxf(acc[nl][q * 4 + 0] * ivd + rv.x + bv.x, 0.f);
    h[1] = fmaxf(acc[nl][q * 4 + 1] * ivd + rv.y + bv.y, 0.f);
    h[2] = fmaxf(acc[nl][q * 4 + 2] * ivd + rv.z + bv.z, 0.f);
    h[3] = fmaxf(acc[nl][q * 4 + 3] * ivd + rv.w + bv.w, 0.f);
    *(float4*)(h1 + gnode * FH + q * 4) = make_float4(h[0], h[1], h[2], h[3]);
    if (q == 0) invd_out[gnode] = ivd;
  } else {
    h[0] = h[1] = h[2] = h[3] = 0.f;
  }

  // BN stats: reduce over stride-4 lane groups (preserves q)
  float s[4], sq[4];
#pragma unroll
  for (int k = 0; k < 4; k++) { s[k] = h[k]; sq[k] = h[k] * h[k]; }
#pragma unroll
  for (int off = 4; off < 64; off <<= 1) {
#pragma unroll
    for (int k = 0; k < 4; k++) {
      s[k] += __shfl_xor(s[k], off);
      sq[k] += __shfl_xor(sq[k], off);
    }
  }
  int t6 = t & 63, w = t >> 6;
  if (t6 < 4) {
#pragma unroll
    for (int k = 0; k < 4; k++) {
      sstat[w][t6 * 4 + k] = s[k];
      sstat[w][16 + t6 * 4 + k] = sq[k];
    }
  }
  __syncthreads();
  if (t < 32)
    partials[b * 32 + t] = sstat[0][t] + sstat[1][t] + sstat[2][t] + sstat[3][t];
}

// ---------------------------------------------------------------------------
// bn1_params: reduce per-block partials then finalize BN1 scale/shift.
// ---------------------------------------------------------------------------
__global__ __launch_bounds__(1024) void bn1_params_kernel(
    const float* __restrict__ partials, int P,
    const float* __restrict__ g1, const float* __restrict__ be1,
    float* __restrict__ scsh) {
  __shared__ float red[32][33];
  __shared__ float tot[32];
  int t = threadIdx.x;
  int ch = t & 31, seg = t >> 5;
  float s = 0.f;
  for (int b = seg; b < P; b += 32) s += partials[b * 32 + ch];
  red[seg][ch] = s;
  __syncthreads();
  if (t < 32) {
    float v = 0.f;
    for (int k = 0; k < 32; k++) v += red[k][t];
    tot[t] = v;
  }
  __syncthreads();
  if (t < FH) {
    float m = tot[t] * (1.0f / NN);
    float var = tot[FH + t] * (1.0f / NN) - m * m;
    float sc = g1[t] * rsqrtf(var + EPS);
    scsh[t] = sc;
    scsh[FH + t] = be1[t] - m * sc;
  }
}

// ---------------------------------------------------------------------------
// proj2: hb = bn1(h1) on the fly, p2 = hb @ W2l.T, r2 = hb @ W2r.T.
// ---------------------------------------------------------------------------
__global__ __launch_bounds__(256) void proj2_kernel(
    const float* __restrict__ h1, const float* __restrict__ scsh,
    const float* __restrict__ W2l, const float* __restrict__ W2r,
    float* __restrict__ p2, float* __restrict__ r2) {
  __shared__ float sWl[FH * FH];
  __shared__ float sWr[FH * FH];
  __shared__ float sc[FH], sh[FH];
  int t = threadIdx.x;
  if (t < FH * FH) {
    sWl[t] = W2l[t];
    sWr[t] = W2r[t];
  }
  if (t < FH) {
    sc[t] = scsh[t];
    sh[t] = scsh[FH + t];
  }
  __syncthreads();

  int n = blockIdx.x * 256 + t;
  if (n >= NN) return;
  float hb[FH];
#pragma unroll
  for (int k = 0; k < FH; k += 4) {
    float4 v = *(const float4*)(h1 + n * FH + k);
    hb[k]     = v.x * sc[k]     + sh[k];
    hb[k + 1] = v.y * sc[k + 1] + sh[k + 1];
    hb[k + 2] = v.z * sc[k + 2] + sh[k + 2];
    hb[k + 3] = v.w * sc[k + 3] + sh[k + 3];
  }
  float po[FH], ro[FH];
#pragma unroll
  for (int j = 0; j < FH; j++) {
    float a = 0.f, b = 0.f;
#pragma unroll
    for (int k = 0; k < FH; k++) {
      a += sWl[j * FH + k] * hb[k];
      b += sWr[j * FH + k] * hb[k];
    }
    po[j] = a; ro[j] = b;
  }
#pragma unroll
  for (int j = 0; j < FH; j += 4) {
    *(float4*)(p2 + n * FH + j) = make_float4(po[j], po[j + 1], po[j + 2], po[j + 3]);
    *(float4*)(r2 + n * FH + j) = make_float4(ro[j], ro[j + 1], ro[j + 2], ro[j + 3]);
  }
}

// ---------------------------------------------------------------------------
// aggC2: bucket aggregation for conv2 + fused graph mean-pool.
// ---------------------------------------------------------------------------
__global__ __launch_bounds__(256) void aggC2_kernel(
    const unsigned int* __restrict__ binned, const int* __restrict__ bucket_base,
    const float* __restrict__ p2, const float* __restrict__ r2,
    const float* __restrict__ b2, const float* __restrict__ invd,
    const int* __restrict__ batch, float* __restrict__ gsum) {
  __shared__ float acc[BKN][FH + 1];
  __shared__ float gpool[8][FH];
  __shared__ int g0s, smaxs;
  int t = threadIdx.x, b = blockIdx.x;
  float* af = &acc[0][0];
  for (int i = t; i < BKN * (FH + 1); i += 256) af[i] = 0.f;
  if (t < 8 * FH) (&gpool[0][0])[t] = 0.f;
  if (t == 0) {
    g0s = batch[b * BKN];
    smaxs = batch[min(b * BKN + BKN - 1, NN - 1)] - batch[b * BKN];
  }
  __syncthreads();

  int ebeg = bucket_base[b], eend = bucket_base[b + 1];
  int c = t & 3;
  int e = ebeg + (t >> 2);
  for (; e + 64 < eend; e += 128) {
    unsigned v0 = binned[e];
    unsigned v1 = binned[e + 64];
    int s0 = v0 & 0x1FFFF, d0 = (v0 >> 17) & (BKN - 1);
    int s1 = v1 & 0x1FFFF, d1 = (v1 >> 17) & (BKN - 1);
    float4 g0 = *(const float4*)(p2 + s0 * FH + c * 4);
    float4 g1 = *(const float4*)(p2 + s1 * FH + c * 4);
    atomicAdd(&acc[d0][c * 4 + 0], g0.x);
    atomicAdd(&acc[d0][c * 4 + 1], g0.y);
    atomicAdd(&acc[d0][c * 4 + 2], g0.z);
    atomicAdd(&acc[d0][c * 4 + 3], g0.w);
    atomicAdd(&acc[d1][c * 4 + 0], g1.x);
    atomicAdd(&acc[d1][c * 4 + 1], g1.y);
    atomicAdd(&acc[d1][c * 4 + 2], g1.z);
    atomicAdd(&acc[d1][c * 4 + 3], g1.w);
  }
  if (e < eend) {
    unsigned v0 = binned[e];
    int s0 = v0 & 0x1FFFF, d0 = (v0 >> 17) & (BKN - 1);
    float4 g0 = *(const float4*)(p2 + s0 * FH + c * 4);
    atomicAdd(&acc[d0][c * 4 + 0], g0.x);
    atomicAdd(&acc[d0][c * 4 + 1], g0.y);
    atomicAdd(&acc[d0][c * 4 + 2], g0.z);
    atomicAdd(&acc[d0][c * 4 + 3], g0.w);
  }
  __syncthreads();

  int nl = t >> 2, q = t & 3;
  int gnode = b * BKN + nl;
  if (gnode < NN) {
    float ivd = invd[gnode];
    float4 rv = *(const float4*)(r2 + gnode * FH + q * 4);
    float4 bv = *(const float4*)(b2 + q * 4);
    float h0 = fmaxf(acc[nl][q * 4 + 0] * ivd + rv.x + bv.x, 0.f);
    float h1v = fmaxf(acc[nl][q * 4 + 1] * ivd + rv.y + bv.y, 0.f);
    float h2 = fmaxf(acc[nl][q * 4 + 2] * ivd + rv.z + bv.z, 0.f);
    float h3 = fmaxf(acc[nl][q * 4 + 3] * ivd + rv.w + bv.w, 0.f);
    int slot = batch[gnode] - g0s;
    if (slot < 8) {
      atomicAdd(&gpool[slot][q * 4 + 0], h0);
      atomicAdd(&gpool[slot][q * 4 + 1], h1v);
      atomicAdd(&gpool[slot][q * 4 + 2], h2);
      atomicAdd(&gpool[slot][q * 4 + 3], h3);
    } else {  // rare: bucket spans >8 graphs
      atomicAdd(gsum + (g0s + slot) * FH + q * 4 + 0, h0);
      atomicAdd(gsum + (g0s + slot) * FH + q * 4 + 1, h1v);
      atomicAdd(gsum + (g0s + slot) * FH + q * 4 + 2, h2);
      atomicAdd(gsum + (g0s + slot) * FH + q * 4 + 3, h3);
    }
  }
  __syncthreads();

  int nslots = smaxs + 1;
  if (t < nslots * FH && t < 8 * FH) {
    int s = t >> 4, ch = t & 15;
    atomicAdd(gsum + (g0s + s) * FH + ch, gpool[s][ch]);
  }
}

// ---------------------------------------------------------------------------
// head: whole D2RL dense head in one block; per-graph counts via binary
// search on sorted batch.
// ---------------------------------------------------------------------------
__global__ __launch_bounds__(256) void head_kernel(
    const float* __restrict__ gsum, const int* __restrict__ batch,
    const float* __restrict__ gn1, const float* __restrict__ bn1,
    const float* __restrict__ Wl1, const float* __restrict__ bl1,
    const float* __restrict__ gn2, const float* __restrict__ bn2,
    const float* __restrict__ Wl2, const float* __restrict__ bl2,
    const float* __restrict__ gn3, const float* __restrict__ bn3,
    const float* __restrict__ Wl3, const float* __restrict__ bl3,
    const float* __restrict__ Wout, const float* __restrict__ bout,
    float* __restrict__ out) {
  __shared__ float sxe[FH * NG];
  __shared__ float sz[FH * NG];
  __shared__ float sz2[FH * NG];
  __shared__ float sc1[FH], sh1[FH], sc2[2 * FH], sh2[2 * FH], sc3[2 * FH], sh3[2 * FH];

  int g = threadIdx.x;
  int lo = 0, hi = NN;
  while (lo < hi) { int mid = (lo + hi) >> 1; if (batch[mid] < g) lo = mid + 1; else hi = mid; }
  int lo2 = lo, hi2 = NN;
  while (lo2 < hi2) { int mid = (lo2 + hi2) >> 1; if (batch[mid] < g + 1) lo2 = mid + 1; else hi2 = mid; }
  float cnt = fmaxf((float)(lo2 - lo), 1.0f);

  float xe[FH];
#pragma unroll
  for (int c = 0; c < FH; c++) {
    xe[c] = gsum[g * FH + c] / cnt;
    sxe[c * NG + g] = xe[c];
  }
  __syncthreads();

  if (g < FH) {
    float s = 0.f, q = 0.f;
    for (int i = 0; i < NG; i++) {
      float v = sxe[g * NG + i];
      s += v; q += v * v;
    }
    float m = s * (1.0f / NG);
    float var = q * (1.0f / NG) - m * m;
    float sc = gn1[g] * rsqrtf(var + EPS);
    sc1[g] = sc;
    sh1[g] = bn1[g] - m * sc;
  }
  __syncthreads();

  float z1[FH];
  {
    float xb[FH];
#pragma unroll
    for (int k = 0; k < FH; k++) xb[k] = xe[k] * sc1[k] + sh1[k];
#pragma unroll
    for (int j = 0; j < FH; j++) {
      float acc = bl1[j];
#pragma unroll
      for (int k = 0; k < FH; k++) acc += Wl1[j * FH + k] * xb[k];
      z1[j] = fmaxf(acc, 0.f);
      sz[j * NG + g] = z1[j];
    }
  }
  __syncthreads();

  if (g < 2 * FH) {
    const float* col = (g < FH) ? (sz + g * NG) : (sxe + (g - FH) * NG);
    float s = 0.f, q = 0.f;
    for (int i = 0; i < NG; i++) {
      float v = col[i];
      s += v; q += v * v;
    }
    float m = s * (1.0f / NG);
    float var = q * (1.0f / NG) - m * m;
    float sc = gn2[g] * rsqrtf(var + EPS);
    sc2[g] = sc;
    sh2[g] = bn2[g] - m * sc;
  }
  __syncthreads();

  float z2[FH];
  {
    float cat[2 * FH];
#pragma unroll
    for (int k = 0; k < FH; k++) {
      cat[k] = z1[k] * sc2[k] + sh2[k];
      cat[FH + k] = xe[k] * sc2[FH + k] + sh2[FH + k];
    }
#pragma unroll
    for (int j = 0; j < FH; j++) {
      float acc = bl2[j];
#pragma unroll
      for (int k = 0; k < 2 * FH; k++) acc += Wl2[j * 2 * FH + k] * cat[k];
      z2[j] = fmaxf(acc, 0.f);
      sz2[j * NG + g] = z2[j];
    }
  }
  __syncthreads();

  if (g < 2 * FH) {
    const float* col = (g < FH) ? (sz2 + g * NG) : (sxe + (g - FH) * NG);
    float s = 0.f, q = 0.f;
    for (int i = 0; i < NG; i++) {
      float v = col[i];
      s += v; q += v * v;
    }
    float m = s * (1.0f / NG);
    float var = q * (1.0f / NG) - m * m;
    float sc = gn3[g] * rsqrtf(var + EPS);
    sc3[g] = sc;
    sh3[g] = bn3[g] - m * sc;
  }
  __syncthreads();

  {
    float cat[2 * FH];
#pragma unroll
    for (int k = 0; k < FH; k++) {
      cat[k] = z2[k] * sc3[k] + sh3[k];
      cat[FH + k] = xe[k] * sc3[FH + k] + sh3[FH + k];
    }
    float o = bout[0];
#pragma unroll
    for (int j = 0; j < FH; j++) {
      float acc = bl3[j];
#pragma unroll
      for (int k = 0; k < 2 * FH; k++) acc += Wl3[j * 2 * FH + k] * cat[k];
      o += Wout[j] * fmaxf(acc, 0.f);
    }
    out[g] = o;
  }
}

// ---------------------------------------------------------------------------
extern "C" void kernel_launch(void* const* d_in, const int* in_sizes, int n_in,
                              void* d_out, int out_size, void* d_ws, size_t ws_size,
                              hipStream_t stream) {
  const float* x    = (const float*)d_in[0];
  const int*   ei   = (const int*)d_in[1];
  const int*   batch= (const int*)d_in[2];
  const float* W1l  = (const float*)d_in[3];
  const float* W1r  = (const float*)d_in[4];
  const float* b1   = (const float*)d_in[5];
  const float* g1   = (const float*)d_in[6];
  const float* be1  = (const float*)d_in[7];
  const float* W2l  = (const float*)d_in[8];
  const float* W2r  = (const float*)d_in[9];
  const float* b2   = (const float*)d_in[10];
  const float* gn1  = (const float*)d_in[11];
  const float* bn1  = (const float*)d_in[12];
  const float* Wl1  = (const float*)d_in[13];
  const float* bl1  = (const float*)d_in[14];
  const float* gn2  = (const float*)d_in[15];
  const float* bn2  = (const float*)d_in[16];
  const float* Wl2  = (const float*)d_in[17];
  const float* bl2  = (const float*)d_in[18];
  const float* gn3  = (const float*)d_in[19];
  const float* bn3  = (const float*)d_in[20];
  const float* Wl3  = (const float*)d_in[21];
  const float* bl3  = (const float*)d_in[22];
  const float* Wout = (const float*)d_in[23];
  const float* bout = (const float*)d_in[24];

  int* wi = (int*)d_ws;
  // zeroed region (one 16KB memset):
  float* gsum        = (float*)wi;                      // [NG*FH] = 4096
  // non-zeroed:
  int*   cntmat      = wi + NG * FH;                    // [NBUK*NAB]
  int*   bucket_cnt  = cntmat + NBUK * NAB;             // [NBUK]
  int*   bucket_base = bucket_cnt + NBUK;               // [NBUK+1]
  unsigned int* binned = (unsigned int*)(bucket_base + NBUK + 1);  // [NE]
  float* invd        = (float*)(binned + NE);           // [NN]
  float* partials    = invd + NN;                       // [NBUK*32]
  float* scsh        = partials + (size_t)NBUK * 32;    // [32]
  float* y1          = scsh + 32;                       // [NN*16] (reused as p2)
  float* r1          = y1 + (size_t)NN * FH;            // [NN*16] (reused as r2)
  float* h1          = r1 + (size_t)NN * FH;            // [NN*16]
  float* p2          = y1;
  float* r2          = r1;

  hipMemsetAsync(d_ws, 0, (size_t)NG * FH * sizeof(float), stream);

  int nodeBlocks = (NN + 255) / 256;

  countA_kernel<<<NAB, 256, 0, stream>>>(ei, cntmat);
  bscan1_kernel<<<(NBUK + 255) / 256, 256, 0, stream>>>(cntmat, bucket_cnt);
  bscan2_kernel<<<1, 1024, 0, stream>>>(bucket_cnt, bucket_base);
  bscan3_kernel<<<(NBUK + 255) / 256, 256, 0, stream>>>(cntmat, bucket_base);
  binB_kernel<<<NAB, 256, 0, stream>>>(ei, cntmat, binned);
  proj1_kernel<<<nodeBlocks, 256, 0, stream>>>(x, W1l, W1r, y1, r1);
  aggC1_kernel<<<NBUK, 256, 0, stream>>>(binned, bucket_base, y1, r1, b1, h1, invd, partials);
  bn1_params_kernel<<<1, 1024, 0, stream>>>(partials, NBUK, g1, be1, scsh);
  proj2_kernel<<<nodeBlocks, 256, 0, stream>>>(h1, scsh, W2l, W2r, p2, r2);
  aggC2_kernel<<<NBUK, 256, 0, stream>>>(binned, bucket_base, p2, r2, b2, invd, batch, gsum);
  head_kernel<<<1, 256, 0, stream>>>(gsum, batch, gn1, bn1, Wl1, bl1,
                                     gn2, bn2, Wl2, bl2, gn3, bn3, Wl3, bl3,
                                     Wout, bout, (float*)d_out);
}

// Round 13
// 561.957 us; speedup vs baseline: 1.0521x; 1.0117x over previous
//
#include <hip/hip_runtime.h>
#include <hip/hip_bf16.h>

#define NN 100000
#define NE 1600000
#define FIN 32
#define FH 16
#define NG 256
#define EPS 1e-5f
#define ABLK 8192                      // edges per binning block
#define NAB ((NE + ABLK - 1) / ABLK)   // 196 binning blocks
#define BKN 64                         // nodes per bucket
#define BSH 6                          // log2(BKN)
#define NBUK ((NN + BKN - 1) / BKN)    // 1563 buckets

// bf16 helpers: gather tables are bf16 so the 100Kx16 table is 3.2MB and
// fits the 4MB per-XCD L2 (r12 lesson: f32 table = 6.4MB thrashed L2,
// FETCH 71MB -> latency-bound aggC at 162us).
static __device__ __forceinline__ unsigned short f2bf(float f) {
  unsigned u = __float_as_uint(f);
  u += 0x7FFFu + ((u >> 16) & 1u);  // RNE
  return (unsigned short)(u >> 16);
}

// ---------------------------------------------------------------------------
// countA: per-(bucket,block) edge counts. LDS histogram, dense writes.
// ---------------------------------------------------------------------------
__global__ __launch_bounds__(256) void countA_kernel(const int* __restrict__ ei,
                                                     int* __restrict__ cntmat) {
  __shared__ int cnt[NBUK];
  int t = threadIdx.x, blk = blockIdx.x;
  for (int i = t; i < NBUK; i += 256) cnt[i] = 0;
  __syncthreads();
  int e0 = blk * ABLK;
  for (int i = 0; i < ABLK / 256; i++) {
    int e = e0 + t + i * 256;
    if (e < NE) atomicAdd(&cnt[ei[NE + e] >> BSH], 1);
  }
  __syncthreads();
  for (int i = t; i < NBUK; i += 256) cntmat[i * NAB + blk] = cnt[i];
}

// ---------------------------------------------------------------------------
// bscan1: bucket totals.
// ---------------------------------------------------------------------------
__global__ __launch_bounds__(256) void bscan1_kernel(const int* __restrict__ cntmat,
                                                     int* __restrict__ bucket_cnt) {
  int b = blockIdx.x * 256 + threadIdx.x;
  if (b >= NBUK) return;
  const int* row = cntmat + b * NAB;
  int s = 0;
  for (int k = 0; k < NAB; k++) s += row[k];
  bucket_cnt[b] = s;
}

// ---------------------------------------------------------------------------
// bscan2: exclusive scan of NBUK(=1563) totals, 2 buckets/thread.
// ---------------------------------------------------------------------------
__global__ __launch_bounds__(1024) void bscan2_kernel(const int* __restrict__ bucket_cnt,
                                                      int* __restrict__ bucket_base) {
  __shared__ int part[1024];
  int t = threadIdx.x;
  int i0 = 2 * t;
  int d0 = (i0 < NBUK) ? bucket_cnt[i0] : 0;
  int d1 = (i0 + 1 < NBUK) ? bucket_cnt[i0 + 1] : 0;
  int ts = d0 + d1;
  part[t] = ts;
  __syncthreads();
  for (int off = 1; off < 1024; off <<= 1) {
    int u = (t >= off) ? part[t - off] : 0;
    __syncthreads();
    part[t] += u;
    __syncthreads();
  }
  int base = part[t] - ts;
  if (i0 < NBUK) bucket_base[i0] = base;
  if (i0 + 1 < NBUK) bucket_base[i0 + 1] = base + d0;
  if (t == 1023) bucket_base[NBUK] = part[1023];
}

// ---------------------------------------------------------------------------
// bscan3: per-(bucket,block) base offsets, in place on cntmat.
// ---------------------------------------------------------------------------
__global__ __launch_bounds__(256) void bscan3_kernel(int* __restrict__ cntmat,
                                                     const int* __restrict__ bucket_base) {
  int b = blockIdx.x * 256 + threadIdx.x;
  if (b >= NBUK) return;
  int acc = bucket_base[b];
  int* row = cntmat + b * NAB;
  for (int k = 0; k < NAB; k++) {
    int c = row[k];
    row[k] = acc;
    acc += c;
  }
}

// ---------------------------------------------------------------------------
// binB: bucket-grouped edge writes, LDS rank counters, no global atomics.
// u32 payload: src(17b) | dst_local(6b)<<17.
// ---------------------------------------------------------------------------
__global__ __launch_bounds__(256) void binB_kernel(const int* __restrict__ ei,
                                                   const int* __restrict__ blockbase,
                                                   unsigned int* __restrict__ binned) {
  __shared__ int base[NBUK];
  __shared__ int cnt2[NBUK];
  int t = threadIdx.x, blk = blockIdx.x;
  for (int i = t; i < NBUK; i += 256) {
    base[i] = blockbase[i * NAB + blk];
    cnt2[i] = 0;
  }
  __syncthreads();
  int e0 = blk * ABLK;
  for (int i = 0; i < ABLK / 256; i++) {
    int e = e0 + t + i * 256;
    if (e < NE) {
      int src = ei[e];
      int dst = ei[NE + e];
      int bk = dst >> BSH;
      int r = atomicAdd(&cnt2[bk], 1);
      binned[base[bk] + r] = (unsigned)src | ((unsigned)(dst & (BKN - 1)) << 17);
    }
  }
}

// ---------------------------------------------------------------------------
// proj1: y1b = bf16(x @ W1l.T)  [the GATHERED table, 3.2MB],
//        r1  = f32(x @ W1r.T)   [coalesced side stays f32].
// ---------------------------------------------------------------------------
__global__ __launch_bounds__(256) void proj1_kernel(
    const float* __restrict__ x,
    const float* __restrict__ W1l, const float* __restrict__ W1r,
    unsigned short* __restrict__ y1b, float* __restrict__ r1) {
  __shared__ float sWl[FH * FIN];
  __shared__ float sWr[FH * FIN];
  int t = threadIdx.x;
  for (int i = t; i < FH * FIN; i += 256) {
    sWl[i] = W1l[i];
    sWr[i] = W1r[i];
  }
  __syncthreads();

  int n = blockIdx.x * 256 + t;
  if (n >= NN) return;
  float xl[FIN];
#pragma unroll
  for (int k = 0; k < FIN; k += 4) {
    float4 v = *(const float4*)(x + n * FIN + k);
    xl[k] = v.x; xl[k + 1] = v.y; xl[k + 2] = v.z; xl[k + 3] = v.w;
  }
  float yo[FH], ro[FH];
#pragma unroll
  for (int j = 0; j < FH; j++) {
    float a = 0.f, b = 0.f;
#pragma unroll
    for (int k = 0; k < FIN; k++) {
      a += sWl[j * FIN + k] * xl[k];
      b += sWr[j * FIN + k] * xl[k];
    }
    yo[j] = a; ro[j] = b;
  }
  unsigned pk[8];
#pragma unroll
  for (int j = 0; j < 8; j++)
    pk[j] = (unsigned)f2bf(yo[2 * j]) | ((unsigned)f2bf(yo[2 * j + 1]) << 16);
  uint4* yd = (uint4*)(y1b + n * FH);
  yd[0] = make_uint4(pk[0], pk[1], pk[2], pk[3]);
  yd[1] = make_uint4(pk[4], pk[5], pk[6], pk[7]);
#pragma unroll
  for (int j = 0; j < FH; j += 4)
    *(float4*)(r1 + n * FH + j) = make_float4(ro[j], ro[j + 1], ro[j + 2], ro[j + 3]);
}

// ---------------------------------------------------------------------------
// aggC1: one 64-node bucket/block; unroll-2 edge loop; bf16 uint2 gathers
// (8B/lane, table L2-resident); LDS f32 accumulation (acc padded FH+1).
// Fused conv1 epilogue + BN partials.
// ---------------------------------------------------------------------------
__global__ __launch_bounds__(256) void aggC1_kernel(
    const unsigned int* __restrict__ binned, const int* __restrict__ bucket_base,
    const unsigned short* __restrict__ y1b, const float* __restrict__ r1,
    const float* __restrict__ b1,
    float* __restrict__ h1, float* __restrict__ invd_out,
    float* __restrict__ partials) {
  __shared__ float acc[BKN][FH + 1];
  __shared__ int cnt[BKN];
  __shared__ float sstat[4][32];
  int t = threadIdx.x, b = blockIdx.x;
  float* af = &acc[0][0];
  for (int i = t; i < BKN * (FH + 1); i += 256) af[i] = 0.f;
  if (t < BKN) cnt[t] = 0;
  __syncthreads();

  const uint2* yb = (const uint2*)y1b;  // 4 bf16 per uint2, row = 4 uint2
  int ebeg = bucket_base[b], eend = bucket_base[b + 1];
  int c = t & 3;
  int e = ebeg + (t >> 2);
  for (; e + 64 < eend; e += 128) {
    unsigned v0 = binned[e];
    unsigned v1 = binned[e + 64];
    int s0 = v0 & 0x1FFFF, d0 = (v0 >> 17) & (BKN - 1);
    int s1 = v1 & 0x1FFFF, d1 = (v1 >> 17) & (BKN - 1);
    uint2 g0 = yb[s0 * 4 + c];
    uint2 g1 = yb[s1 * 4 + c];
    atomicAdd(&acc[d0][c * 4 + 0], __uint_as_float((g0.x & 0xFFFFu) << 16));
    atomicAdd(&acc[d0][c * 4 + 1], __uint_as_float(g0.x & 0xFFFF0000u));
    atomicAdd(&acc[d0][c * 4 + 2], __uint_as_float((g0.y & 0xFFFFu) << 16));
    atomicAdd(&acc[d0][c * 4 + 3], __uint_as_float(g0.y & 0xFFFF0000u));
    atomicAdd(&acc[d1][c * 4 + 0], __uint_as_float((g1.x & 0xFFFFu) << 16));
    atomicAdd(&acc[d1][c * 4 + 1], __uint_as_float(g1.x & 0xFFFF0000u));
    atomicAdd(&acc[d1][c * 4 + 2], __uint_as_float((g1.y & 0xFFFFu) << 16));
    atomicAdd(&acc[d1][c * 4 + 3], __uint_as_float(g1.y & 0xFFFF0000u));
    if (c == 0) {
      atomicAdd(&cnt[d0], 1);
      atomicAdd(&cnt[d1], 1);
    }
  }
  if (e < eend) {
    unsigned v0 = binned[e];
    int s0 = v0 & 0x1FFFF, d0 = (v0 >> 17) & (BKN - 1);
    uint2 g0 = yb[s0 * 4 + c];
    atomicAdd(&acc[d0][c * 4 + 0], __uint_as_float((g0.x & 0xFFFFu) << 16));
    atomicAdd(&acc[d0][c * 4 + 1], __uint_as_float(g0.x & 0xFFFF0000u));
    atomicAdd(&acc[d0][c * 4 + 2], __uint_as_float((g0.y & 0xFFFFu) << 16));
    atomicAdd(&acc[d0][c * 4 + 3], __uint_as_float(g0.y & 0xFFFF0000u));
    if (c == 0) atomicAdd(&cnt[d0], 1);
  }
  __syncthreads();

  // conv1 epilogue: 4 threads/node, 4 channels each
  int nl = t >> 2, q = t & 3;
  int gnode = b * BKN + nl;
  float h[4];
  if (gnode < NN) {
    float ivd = 1.0f / (float)max(cnt[nl], 1);
    float4 rv = *(const float4*)(r1 + gnode * FH + q * 4);
    float4 bv = *(const float4*)(b1 + q * 4);
    h[0] = fmaxf(acc[nl][q * 4 + 0] * ivd + rv.x + bv.x, 0.f);
    h[1] = fmaxf(acc[nl][q * 4 + 1] * ivd + rv.y + bv.y, 0.f);
    h[2] = fmaxf(acc[nl][q * 4 + 2] * ivd + rv.z + bv.z, 0.f);
    h[3] = fmaxf(acc[nl][q * 4 + 3] * ivd + rv.w + bv.w, 0.f);
    *(float4*)(h1 + gnode * FH + q * 4) = make_float4(h[0], h[1], h[2], h[3]);
    if (q == 0) invd_out[gnode] = ivd;
  } else {
    h[0] = h[1] = h[2] = h[3] = 0.f;
  }

  float s[4], sq[4];
#pragma unroll
  for (int k = 0; k < 4; k++) { s[k] = h[k]; sq[k] = h[k] * h[k]; }
#pragma unroll
  for (int off = 4; off < 64; off <<= 1) {
#pragma unroll
    for (int k = 0; k < 4; k++) {
      s[k] += __shfl_xor(s[k], off);
      sq[k] += __shfl_xor(sq[k], off);
    }
  }
  int t6 = t & 63, w = t >> 6;
  if (t6 < 4) {
#pragma unroll
    for (int k = 0; k < 4; k++) {
      sstat[w][t6 * 4 + k] = s[k];
      sstat[w][16 + t6 * 4 + k] = sq[k];
    }
  }
  __syncthreads();
  if (t < 32)
    partials[b * 32 + t] = sstat[0][t] + sstat[1][t] + sstat[2][t] + sstat[3][t];
}

// ---------------------------------------------------------------------------
// bn1_params: reduce per-block partials then finalize BN1 scale/shift.
// ---------------------------------------------------------------------------
__global__ __launch_bounds__(1024) void bn1_params_kernel(
    const float* __restrict__ partials, int P,
    const float* __restrict__ g1, const float* __restrict__ be1,
    float* __restrict__ scsh) {
  __shared__ float red[32][33];
  __shared__ float tot[32];
  int t = threadIdx.x;
  int ch = t & 31, seg = t >> 5;
  float s = 0.f;
  for (int b = seg; b < P; b += 32) s += partials[b * 32 + ch];
  red[seg][ch] = s;
  __syncthreads();
  if (t < 32) {
    float v = 0.f;
    for (int k = 0; k < 32; k++) v += red[k][t];
    tot[t] = v;
  }
  __syncthreads();
  if (t < FH) {
    float m = tot[t] * (1.0f / NN);
    float var = tot[FH + t] * (1.0f / NN) - m * m;
    float sc = g1[t] * rsqrtf(var + EPS);
    scsh[t] = sc;
    scsh[FH + t] = be1[t] - m * sc;
  }
}

// ---------------------------------------------------------------------------
// proj2: hb = bn1(h1) on the fly; p2b = bf16(hb @ W2l.T), r2 = f32(hb @ W2r.T).
// ---------------------------------------------------------------------------
__global__ __launch_bounds__(256) void proj2_kernel(
    const float* __restrict__ h1, const float* __restrict__ scsh,
    const float* __restrict__ W2l, const float* __restrict__ W2r,
    unsigned short* __restrict__ p2b, float* __restrict__ r2) {
  __shared__ float sWl[FH * FH];
  __shared__ float sWr[FH * FH];
  __shared__ float sc[FH], sh[FH];
  int t = threadIdx.x;
  if (t < FH * FH) {
    sWl[t] = W2l[t];
    sWr[t] = W2r[t];
  }
  if (t < FH) {
    sc[t] = scsh[t];
    sh[t] = scsh[FH + t];
  }
  __syncthreads();

  int n = blockIdx.x * 256 + t;
  if (n >= NN) return;
  float hb[FH];
#pragma unroll
  for (int k = 0; k < FH; k += 4) {
    float4 v = *(const float4*)(h1 + n * FH + k);
    hb[k]     = v.x * sc[k]     + sh[k];
    hb[k + 1] = v.y * sc[k + 1] + sh[k + 1];
    hb[k + 2] = v.z * sc[k + 2] + sh[k + 2];
    hb[k + 3] = v.w * sc[k + 3] + sh[k + 3];
  }
  float po[FH], ro[FH];
#pragma unroll
  for (int j = 0; j < FH; j++) {
    float a = 0.f, b = 0.f;
#pragma unroll
    for (int k = 0; k < FH; k++) {
      a += sWl[j * FH + k] * hb[k];
      b += sWr[j * FH + k] * hb[k];
    }
    po[j] = a; ro[j] = b;
  }
  unsigned pk[8];
#pragma unroll
  for (int j = 0; j < 8; j++)
    pk[j] = (unsigned)f2bf(po[2 * j]) | ((unsigned)f2bf(po[2 * j + 1]) << 16);
  uint4* pd = (uint4*)(p2b + n * FH);
  pd[0] = make_uint4(pk[0], pk[1], pk[2], pk[3]);
  pd[1] = make_uint4(pk[4], pk[5], pk[6], pk[7]);
#pragma unroll
  for (int j = 0; j < FH; j += 4)
    *(float4*)(r2 + n * FH + j) = make_float4(ro[j], ro[j + 1], ro[j + 2], ro[j + 3]);
}

// ---------------------------------------------------------------------------
// aggC2: bucket aggregation for conv2 (bf16 gathers) + fused graph mean-pool.
// ---------------------------------------------------------------------------
__global__ __launch_bounds__(256) void aggC2_kernel(
    const unsigned int* __restrict__ binned, const int* __restrict__ bucket_base,
    const unsigned short* __restrict__ p2b, const float* __restrict__ r2,
    const float* __restrict__ b2, const float* __restrict__ invd,
    const int* __restrict__ batch, float* __restrict__ gsum) {
  __shared__ float acc[BKN][FH + 1];
  __shared__ float gpool[8][FH];
  __shared__ int g0s, smaxs;
  int t = threadIdx.x, b = blockIdx.x;
  float* af = &acc[0][0];
  for (int i = t; i < BKN * (FH + 1); i += 256) af[i] = 0.f;
  if (t < 8 * FH) (&gpool[0][0])[t] = 0.f;
  if (t == 0) {
    g0s = batch[b * BKN];
    smaxs = batch[min(b * BKN + BKN - 1, NN - 1)] - batch[b * BKN];
  }
  __syncthreads();

  const uint2* pb = (const uint2*)p2b;
  int ebeg = bucket_base[b], eend = bucket_base[b + 1];
  int c = t & 3;
  int e = ebeg + (t >> 2);
  for (; e + 64 < eend; e += 128) {
    unsigned v0 = binned[e];
    unsigned v1 = binned[e + 64];
    int s0 = v0 & 0x1FFFF, d0 = (v0 >> 17) & (BKN - 1);
    int s1 = v1 & 0x1FFFF, d1 = (v1 >> 17) & (BKN - 1);
    uint2 g0 = pb[s0 * 4 + c];
    uint2 g1 = pb[s1 * 4 + c];
    atomicAdd(&acc[d0][c * 4 + 0], __uint_as_float((g0.x & 0xFFFFu) << 16));
    atomicAdd(&acc[d0][c * 4 + 1], __uint_as_float(g0.x & 0xFFFF0000u));
    atomicAdd(&acc[d0][c * 4 + 2], __uint_as_float((g0.y & 0xFFFFu) << 16));
    atomicAdd(&acc[d0][c * 4 + 3], __uint_as_float(g0.y & 0xFFFF0000u));
    atomicAdd(&acc[d1][c * 4 + 0], __uint_as_float((g1.x & 0xFFFFu) << 16));
    atomicAdd(&acc[d1][c * 4 + 1], __uint_as_float(g1.x & 0xFFFF0000u));
    atomicAdd(&acc[d1][c * 4 + 2], __uint_as_float((g1.y & 0xFFFFu) << 16));
    atomicAdd(&acc[d1][c * 4 + 3], __uint_as_float(g1.y & 0xFFFF0000u));
  }
  if (e < eend) {
    unsigned v0 = binned[e];
    int s0 = v0 & 0x1FFFF, d0 = (v0 >> 17) & (BKN - 1);
    uint2 g0 = pb[s0 * 4 + c];
    atomicAdd(&acc[d0][c * 4 + 0], __uint_as_float((g0.x & 0xFFFFu) << 16));
    atomicAdd(&acc[d0][c * 4 + 1], __uint_as_float(g0.x & 0xFFFF0000u));
    atomicAdd(&acc[d0][c * 4 + 2], __uint_as_float((g0.y & 0xFFFFu) << 16));
    atomicAdd(&acc[d0][c * 4 + 3], __uint_as_float(g0.y & 0xFFFF0000u));
  }
  __syncthreads();

  int nl = t >> 2, q = t & 3;
  int gnode = b * BKN + nl;
  if (gnode < NN) {
    float ivd = invd[gnode];
    float4 rv = *(const float4*)(r2 + gnode * FH + q * 4);
    float4 bv = *(const float4*)(b2 + q * 4);
    float h0 = fmaxf(acc[nl][q * 4 + 0] * ivd + rv.x + bv.x, 0.f);
    float h1v = fmaxf(acc[nl][q * 4 + 1] * ivd + rv.y + bv.y, 0.f);
    float h2 = fmaxf(acc[nl][q * 4 + 2] * ivd + rv.z + bv.z, 0.f);
    float h3 = fmaxf(acc[nl][q * 4 + 3] * ivd + rv.w + bv.w, 0.f);
    int slot = batch[gnode] - g0s;
    if (slot < 8) {
      atomicAdd(&gpool[slot][q * 4 + 0], h0);
      atomicAdd(&gpool[slot][q * 4 + 1], h1v);
      atomicAdd(&gpool[slot][q * 4 + 2], h2);
      atomicAdd(&gpool[slot][q * 4 + 3], h3);
    } else {  // rare: bucket spans >8 graphs
      atomicAdd(gsum + (g0s + slot) * FH + q * 4 + 0, h0);
      atomicAdd(gsum + (g0s + slot) * FH + q * 4 + 1, h1v);
      atomicAdd(gsum + (g0s + slot) * FH + q * 4 + 2, h2);
      atomicAdd(gsum + (g0s + slot) * FH + q * 4 + 3, h3);
    }
  }
  __syncthreads();

  int nslots = smaxs + 1;
  if (t < nslots * FH && t < 8 * FH) {
    int s = t >> 4, ch = t & 15;
    atomicAdd(gsum + (g0s + s) * FH + ch, gpool[s][ch]);
  }
}

// ---------------------------------------------------------------------------
// head: whole D2RL dense head in one block; per-graph counts via binary
// search on sorted batch.
// ---------------------------------------------------------------------------
__global__ __launch_bounds__(256) void head_kernel(
    const float* __restrict__ gsum, const int* __restrict__ batch,
    const float* __restrict__ gn1, const float* __restrict__ bn1,
    const float* __restrict__ Wl1, const float* __restrict__ bl1,
    const float* __restrict__ gn2, const float* __restrict__ bn2,
    const float* __restrict__ Wl2, const float* __restrict__ bl2,
    const float* __restrict__ gn3, const float* __restrict__ bn3,
    const float* __restrict__ Wl3, const float* __restrict__ bl3,
    const float* __restrict__ Wout, const float* __restrict__ bout,
    float* __restrict__ out) {
  __shared__ float sxe[FH * NG];
  __shared__ float sz[FH * NG];
  __shared__ float sz2[FH * NG];
  __shared__ float sc1[FH], sh1[FH], sc2[2 * FH], sh2[2 * FH], sc3[2 * FH], sh3[2 * FH];

  int g = threadIdx.x;
  int lo = 0, hi = NN;
  while (lo < hi) { int mid = (lo + hi) >> 1; if (batch[mid] < g) lo = mid + 1; else hi = mid; }
  int lo2 = lo, hi2 = NN;
  while (lo2 < hi2) { int mid = (lo2 + hi2) >> 1; if (batch[mid] < g + 1) lo2 = mid + 1; else hi2 = mid; }
  float cnt = fmaxf((float)(lo2 - lo), 1.0f);

  float xe[FH];
#pragma unroll
  for (int c = 0; c < FH; c++) {
    xe[c] = gsum[g * FH + c] / cnt;
    sxe[c * NG + g] = xe[c];
  }
  __syncthreads();

  if (g < FH) {
    float s = 0.f, q = 0.f;
    for (int i = 0; i < NG; i++) {
      float v = sxe[g * NG + i];
      s += v; q += v * v;
    }
    float m = s * (1.0f / NG);
    float var = q * (1.0f / NG) - m * m;
    float sc = gn1[g] * rsqrtf(var + EPS);
    sc1[g] = sc;
    sh1[g] = bn1[g] - m * sc;
  }
  __syncthreads();

  float z1[FH];
  {
    float xb[FH];
#pragma unroll
    for (int k = 0; k < FH; k++) xb[k] = xe[k] * sc1[k] + sh1[k];
#pragma unroll
    for (int j = 0; j < FH; j++) {
      float acc = bl1[j];
#pragma unroll
      for (int k = 0; k < FH; k++) acc += Wl1[j * FH + k] * xb[k];
      z1[j] = fmaxf(acc, 0.f);
      sz[j * NG + g] = z1[j];
    }
  }
  __syncthreads();

  if (g < 2 * FH) {
    const float* col = (g < FH) ? (sz + g * NG) : (sxe + (g - FH) * NG);
    float s = 0.f, q = 0.f;
    for (int i = 0; i < NG; i++) {
      float v = col[i];
      s += v; q += v * v;
    }
    float m = s * (1.0f / NG);
    float var = q * (1.0f / NG) - m * m;
    float sc = gn2[g] * rsqrtf(var + EPS);
    sc2[g] = sc;
    sh2[g] = bn2[g] - m * sc;
  }
  __syncthreads();

  float z2[FH];
  {
    float cat[2 * FH];
#pragma unroll
    for (int k = 0; k < FH; k++) {
      cat[k] = z1[k] * sc2[k] + sh2[k];
      cat[FH + k] = xe[k] * sc2[FH + k] + sh2[FH + k];
    }
#pragma unroll
    for (int j = 0; j < FH; j++) {
      float acc = bl2[j];
#pragma unroll
      for (int k = 0; k < 2 * FH; k++) acc += Wl2[j * 2 * FH + k] * cat[k];
      z2[j] = fmaxf(acc, 0.f);
      sz2[j * NG + g] = z2[j];
    }
  }
  __syncthreads();

  if (g < 2 * FH) {
    const float* col = (g < FH) ? (sz2 + g * NG) : (sxe + (g - FH) * NG);
    float s = 0.f, q = 0.f;
    for (int i = 0; i < NG; i++) {
      float v = col[i];
      s += v; q += v * v;
    }
    float m = s * (1.0f / NG);
    float var = q * (1.0f / NG) - m * m;
    float sc = gn3[g] * rsqrtf(var + EPS);
    sc3[g] = sc;
    sh3[g] = bn3[g] - m * sc;
  }
  __syncthreads();

  {
    float cat[2 * FH];
#pragma unroll
    for (int k = 0; k < FH; k++) {
      cat[k] = z2[k] * sc3[k] + sh3[k];
      cat[FH + k] = xe[k] * sc3[FH + k] + sh3[FH + k];
    }
    float o = bout[0];
#pragma unroll
    for (int j = 0; j < FH; j++) {
      float acc = bl3[j];
#pragma unroll
      for (int k = 0; k < 2 * FH; k++) acc += Wl3[j * 2 * FH + k] * cat[k];
      o += Wout[j] * fmaxf(acc, 0.f);
    }
    out[g] = o;
  }
}

// ---------------------------------------------------------------------------
extern "C" void kernel_launch(void* const* d_in, const int* in_sizes, int n_in,
                              void* d_out, int out_size, void* d_ws, size_t ws_size,
                              hipStream_t stream) {
  const float* x    = (const float*)d_in[0];
  const int*   ei   = (const int*)d_in[1];
  const int*   batch= (const int*)d_in[2];
  const float* W1l  = (const float*)d_in[3];
  const float* W1r  = (const float*)d_in[4];
  const float* b1   = (const float*)d_in[5];
  const float* g1   = (const float*)d_in[6];
  const float* be1  = (const float*)d_in[7];
  const float* W2l  = (const float*)d_in[8];
  const float* W2r  = (const float*)d_in[9];
  const float* b2   = (const float*)d_in[10];
  const float* gn1  = (const float*)d_in[11];
  const float* bn1  = (const float*)d_in[12];
  const float* Wl1  = (const float*)d_in[13];
  const float* bl1  = (const float*)d_in[14];
  const float* gn2  = (const float*)d_in[15];
  const float* bn2  = (const float*)d_in[16];
  const float* Wl2  = (const float*)d_in[17];
  const float* bl2  = (const float*)d_in[18];
  const float* gn3  = (const float*)d_in[19];
  const float* bn3  = (const float*)d_in[20];
  const float* Wl3  = (const float*)d_in[21];
  const float* bl3  = (const float*)d_in[22];
  const float* Wout = (const float*)d_in[23];
  const float* bout = (const float*)d_in[24];

  int* wi = (int*)d_ws;
  size_t off = 0;
  float* gsum        = (float*)(wi + off); off += NG * FH;          // zeroed
  int*   cntmat      = wi + off;           off += (size_t)NBUK * NAB;
  int*   bucket_cnt  = wi + off;           off += NBUK;
  int*   bucket_base = wi + off;           off += NBUK + 1;
  unsigned int* binned = (unsigned int*)(wi + off); off += NE;
  float* invd        = (float*)(wi + off); off += NN;
  float* partials    = (float*)(wi + off); off += (size_t)NBUK * 32;
  float* scsh        = (float*)(wi + off); off += 32;
  off = (off + 3) & ~(size_t)3;                                     // 16B align
  unsigned short* y1b = (unsigned short*)(wi + off); off += (size_t)NN * FH / 2;
  float* r1          = (float*)(wi + off); off += (size_t)NN * FH;
  float* h1          = (float*)(wi + off); off += (size_t)NN * FH;
  unsigned short* p2b = y1b;   // reuse
  float* r2           = r1;    // reuse

  hipMemsetAsync(d_ws, 0, (size_t)NG * FH * sizeof(float), stream);

  int nodeBlocks = (NN + 255) / 256;

  countA_kernel<<<NAB, 256, 0, stream>>>(ei, cntmat);
  bscan1_kernel<<<(NBUK + 255) / 256, 256, 0, stream>>>(cntmat, bucket_cnt);
  bscan2_kernel<<<1, 1024, 0, stream>>>(bucket_cnt, bucket_base);
  bscan3_kernel<<<(NBUK + 255) / 256, 256, 0, stream>>>(cntmat, bucket_base);
  binB_kernel<<<NAB, 256, 0, stream>>>(ei, cntmat, binned);
  proj1_kernel<<<nodeBlocks, 256, 0, stream>>>(x, W1l, W1r, y1b, r1);
  aggC1_kernel<<<NBUK, 256, 0, stream>>>(binned, bucket_base, y1b, r1, b1, h1, invd, partials);
  bn1_params_kernel<<<1, 1024, 0, stream>>>(partials, NBUK, g1, be1, scsh);
  proj2_kernel<<<nodeBlocks, 256, 0, stream>>>(h1, scsh, W2l, W2r, p2b, r2);
  aggC2_kernel<<<NBUK, 256, 0, stream>>>(binned, bucket_base, p2b, r2, b2, invd, batch, gsum);
  head_kernel<<<1, 256, 0, stream>>>(gsum, batch, gn1, bn1, Wl1, bl1,
                                     gn2, bn2, Wl2, bl2, gn3, bn3, Wl3, bl3,
                                     Wout, bout, (float*)d_out);
}

// Round 15
// 295.394 us; speedup vs baseline: 2.0015x; 1.9024x over previous
//
#include <hip/hip_runtime.h>
#include <hip/hip_bf16.h>

#define NN 100000
#define NE 1600000
#define FIN 32
#define FH 16
#define NG 256
#define EPS 1e-5f
#define ABLK 8192                      // edges per binning block
#define NAB ((NE + ABLK - 1) / ABLK)   // 196 binning blocks
#define BKN 64                         // nodes per bucket
#define BSH 6                          // log2(BKN)
#define NBUK ((NN + BKN - 1) / BKN)    // 1563 buckets

// bf16 gather tables: 100Kx16 bf16 = 3.2MB, per-XCD-L2 resident (r13 verified:
// FETCH 71->20MB). r13 lesson: agg time was NOT fetch-bound -- the 25.6M LDS
// atomic lane-ops (3.9 cyc each) were the wall. This version has ZERO atomics
// in the edge loop: binC node-sorts edges within each bucket, sage kernels
// register-accumulate per node.
static __device__ __forceinline__ unsigned short f2bf(float f) {
  unsigned u = __float_as_uint(f);
  u += 0x7FFFu + ((u >> 16) & 1u);  // RNE
  return (unsigned short)(u >> 16);
}

// ---------------------------------------------------------------------------
// countA: per-(bucket,block) edge counts. LDS histogram, dense writes.
// ---------------------------------------------------------------------------
__global__ __launch_bounds__(256) void countA_kernel(const int* __restrict__ ei,
                                                     int* __restrict__ cntmat) {
  __shared__ int cnt[NBUK];
  int t = threadIdx.x, blk = blockIdx.x;
  for (int i = t; i < NBUK; i += 256) cnt[i] = 0;
  __syncthreads();
  int e0 = blk * ABLK;
  for (int i = 0; i < ABLK / 256; i++) {
    int e = e0 + t + i * 256;
    if (e < NE) atomicAdd(&cnt[ei[NE + e] >> BSH], 1);
  }
  __syncthreads();
  for (int i = t; i < NBUK; i += 256) cntmat[i * NAB + blk] = cnt[i];
}

// ---------------------------------------------------------------------------
// bscan1: bucket totals.
// ---------------------------------------------------------------------------
__global__ __launch_bounds__(256) void bscan1_kernel(const int* __restrict__ cntmat,
                                                     int* __restrict__ bucket_cnt) {
  int b = blockIdx.x * 256 + threadIdx.x;
  if (b >= NBUK) return;
  const int* row = cntmat + b * NAB;
  int s = 0;
  for (int k = 0; k < NAB; k++) s += row[k];
  bucket_cnt[b] = s;
}

// ---------------------------------------------------------------------------
// bscan2: exclusive scan of NBUK(=1563) totals, 2 buckets/thread.
// ---------------------------------------------------------------------------
__global__ __launch_bounds__(1024) void bscan2_kernel(const int* __restrict__ bucket_cnt,
                                                      int* __restrict__ bucket_base) {
  __shared__ int part[1024];
  int t = threadIdx.x;
  int i0 = 2 * t;
  int d0 = (i0 < NBUK) ? bucket_cnt[i0] : 0;
  int d1 = (i0 + 1 < NBUK) ? bucket_cnt[i0 + 1] : 0;
  int ts = d0 + d1;
  part[t] = ts;
  __syncthreads();
  for (int off = 1; off < 1024; off <<= 1) {
    int u = (t >= off) ? part[t - off] : 0;
    __syncthreads();
    part[t] += u;
    __syncthreads();
  }
  int base = part[t] - ts;
  if (i0 < NBUK) bucket_base[i0] = base;
  if (i0 + 1 < NBUK) bucket_base[i0 + 1] = base + d0;
  if (t == 1023) bucket_base[NBUK] = part[1023];
}

// ---------------------------------------------------------------------------
// bscan3: per-(bucket,block) base offsets, in place on cntmat.
// ---------------------------------------------------------------------------
__global__ __launch_bounds__(256) void bscan3_kernel(int* __restrict__ cntmat,
                                                     const int* __restrict__ bucket_base) {
  int b = blockIdx.x * 256 + threadIdx.x;
  if (b >= NBUK) return;
  int acc = bucket_base[b];
  int* row = cntmat + b * NAB;
  for (int k = 0; k < NAB; k++) {
    int c = row[k];
    row[k] = acc;
    acc += c;
  }
}

// ---------------------------------------------------------------------------
// binB: bucket-grouped edge writes, LDS rank counters, no global atomics.
// u32 payload: src(17b) | dst_local(6b)<<17.
// ---------------------------------------------------------------------------
__global__ __launch_bounds__(256) void binB_kernel(const int* __restrict__ ei,
                                                   const int* __restrict__ blockbase,
                                                   unsigned int* __restrict__ binned) {
  __shared__ int base[NBUK];
  __shared__ int cnt2[NBUK];
  int t = threadIdx.x, blk = blockIdx.x;
  for (int i = t; i < NBUK; i += 256) {
    base[i] = blockbase[i * NAB + blk];
    cnt2[i] = 0;
  }
  __syncthreads();
  int e0 = blk * ABLK;
  for (int i = 0; i < ABLK / 256; i++) {
    int e = e0 + t + i * 256;
    if (e < NE) {
      int src = ei[e];
      int dst = ei[NE + e];
      int bk = dst >> BSH;
      int r = atomicAdd(&cnt2[bk], 1);
      binned[base[bk] + r] = (unsigned)src | ((unsigned)(dst & (BKN - 1)) << 17);
    }
  }
}

// ---------------------------------------------------------------------------
// binC: within each bucket, group edges by destination node.
// LDS count -> serial 64-scan -> rank scatter. Emits nstart[] (global
// monotone CSR offsets) and binned2[] (node-grouped src ids). Writes land
// inside the bucket's own ~4KB window -> dense at HBM.
// ---------------------------------------------------------------------------
__global__ __launch_bounds__(256) void binC_kernel(
    const unsigned int* __restrict__ binned, const int* __restrict__ bucket_base,
    int* __restrict__ nstart, unsigned int* __restrict__ binned2) {
  __shared__ int lcnt[BKN];
  __shared__ int lscan[BKN];
  int t = threadIdx.x, b = blockIdx.x;
  if (t < BKN) lcnt[t] = 0;
  __syncthreads();
  int ebeg = bucket_base[b], eend = bucket_base[b + 1];
  for (int e = ebeg + t; e < eend; e += 256)
    atomicAdd(&lcnt[(binned[e] >> 17) & (BKN - 1)], 1);
  __syncthreads();
  if (t == 0) {
    int acc = 0;
    for (int i = 0; i < BKN; i++) { lscan[i] = acc; acc += lcnt[i]; }
  }
  __syncthreads();
  int gnode = b * BKN + t;
  if (t < BKN && gnode < NN) nstart[gnode] = ebeg + lscan[t];
  if (b == NBUK - 1 && t == 0) nstart[NN] = NE;
  if (t < BKN) lcnt[t] = lscan[t];  // reuse as rank cursor
  __syncthreads();
  for (int e = ebeg + t; e < eend; e += 256) {
    unsigned v = binned[e];
    int dl = (v >> 17) & (BKN - 1);
    int r = atomicAdd(&lcnt[dl], 1);
    binned2[ebeg + r] = v & 0x1FFFF;
  }
}

// ---------------------------------------------------------------------------
// proj1: y1b = bf16(x @ W1l.T) [gathered table], r1 = f32(x @ W1r.T).
// ---------------------------------------------------------------------------
__global__ __launch_bounds__(256) void proj1_kernel(
    const float* __restrict__ x,
    const float* __restrict__ W1l, const float* __restrict__ W1r,
    unsigned short* __restrict__ y1b, float* __restrict__ r1) {
  __shared__ float sWl[FH * FIN];
  __shared__ float sWr[FH * FIN];
  int t = threadIdx.x;
  for (int i = t; i < FH * FIN; i += 256) {
    sWl[i] = W1l[i];
    sWr[i] = W1r[i];
  }
  __syncthreads();

  int n = blockIdx.x * 256 + t;
  if (n >= NN) return;
  float xl[FIN];
#pragma unroll
  for (int k = 0; k < FIN; k += 4) {
    float4 v = *(const float4*)(x + n * FIN + k);
    xl[k] = v.x; xl[k + 1] = v.y; xl[k + 2] = v.z; xl[k + 3] = v.w;
  }
  float yo[FH], ro[FH];
#pragma unroll
  for (int j = 0; j < FH; j++) {
    float a = 0.f, b = 0.f;
#pragma unroll
    for (int k = 0; k < FIN; k++) {
      a += sWl[j * FIN + k] * xl[k];
      b += sWr[j * FIN + k] * xl[k];
    }
    yo[j] = a; ro[j] = b;
  }
  unsigned pk[8];
#pragma unroll
  for (int j = 0; j < 8; j++)
    pk[j] = (unsigned)f2bf(yo[2 * j]) | ((unsigned)f2bf(yo[2 * j + 1]) << 16);
  uint4* yd = (uint4*)(y1b + n * FH);
  yd[0] = make_uint4(pk[0], pk[1], pk[2], pk[3]);
  yd[1] = make_uint4(pk[4], pk[5], pk[6], pk[7]);
#pragma unroll
  for (int j = 0; j < FH; j += 4)
    *(float4*)(r1 + n * FH + j) = make_float4(ro[j], ro[j + 1], ro[j + 2], ro[j + 3]);
}

// ---------------------------------------------------------------------------
// sageC1: 4 lanes/node, REGISTER accumulation over the node's contiguous
// edge list (no atomics). bf16 uint2 gathers; edge-index reads broadcast
// across the 4-lane group. Fused conv1 epilogue + BN partials.
// ---------------------------------------------------------------------------
__global__ __launch_bounds__(256) void sageC1_kernel(
    const unsigned int* __restrict__ binned2, const int* __restrict__ nstart,
    const unsigned short* __restrict__ y1b, const float* __restrict__ r1,
    const float* __restrict__ b1,
    float* __restrict__ h1, float* __restrict__ partials) {
  __shared__ float sstat[4][32];
  int t = threadIdx.x;
  int gid = blockIdx.x * 256 + t;
  int n = gid >> 2;
  int c = gid & 3;
  const uint2* yb = (const uint2*)y1b;

  float h[4] = {0.f, 0.f, 0.f, 0.f};
  if (n < NN) {
    int beg = nstart[n], end = nstart[n + 1];
    float ivd = 1.0f / (float)max(end - beg, 1);
    float a0 = 0.f, a1 = 0.f, a2 = 0.f, a3 = 0.f;
    int e = beg;
    for (; e + 1 < end; e += 2) {  // unroll-2: two gathers in flight
      int s0 = binned2[e], s1 = binned2[e + 1];
      uint2 g0 = yb[s0 * 4 + c];
      uint2 g1 = yb[s1 * 4 + c];
      a0 += __uint_as_float((g0.x & 0xFFFFu) << 16) + __uint_as_float((g1.x & 0xFFFFu) << 16);
      a1 += __uint_as_float(g0.x & 0xFFFF0000u) + __uint_as_float(g1.x & 0xFFFF0000u);
      a2 += __uint_as_float((g0.y & 0xFFFFu) << 16) + __uint_as_float((g1.y & 0xFFFFu) << 16);
      a3 += __uint_as_float(g0.y & 0xFFFF0000u) + __uint_as_float(g1.y & 0xFFFF0000u);
    }
    if (e < end) {
      uint2 g0 = yb[binned2[e] * 4 + c];
      a0 += __uint_as_float((g0.x & 0xFFFFu) << 16);
      a1 += __uint_as_float(g0.x & 0xFFFF0000u);
      a2 += __uint_as_float((g0.y & 0xFFFFu) << 16);
      a3 += __uint_as_float(g0.y & 0xFFFF0000u);
    }
    float4 rv = *(const float4*)(r1 + n * FH + c * 4);
    float4 bv = *(const float4*)(b1 + c * 4);
    h[0] = fmaxf(a0 * ivd + rv.x + bv.x, 0.f);
    h[1] = fmaxf(a1 * ivd + rv.y + bv.y, 0.f);
    h[2] = fmaxf(a2 * ivd + rv.z + bv.z, 0.f);
    h[3] = fmaxf(a3 * ivd + rv.w + bv.w, 0.f);
    *(float4*)(h1 + n * FH + c * 4) = make_float4(h[0], h[1], h[2], h[3]);
  }

  // BN stats: reduce over stride-4 lane groups (preserves c)
  float s[4], q[4];
#pragma unroll
  for (int j = 0; j < 4; j++) { s[j] = h[j]; q[j] = h[j] * h[j]; }
#pragma unroll
  for (int off = 4; off < 64; off <<= 1) {
#pragma unroll
    for (int j = 0; j < 4; j++) {
      s[j] += __shfl_xor(s[j], off);
      q[j] += __shfl_xor(q[j], off);
    }
  }
  int t6 = t & 63, w = t >> 6;
  if (t6 < 4) {
#pragma unroll
    for (int j = 0; j < 4; j++) {
      sstat[w][t6 * 4 + j] = s[j];
      sstat[w][16 + t6 * 4 + j] = q[j];
    }
  }
  __syncthreads();
  if (t < 32)
    partials[blockIdx.x * 32 + t] =
        sstat[0][t] + sstat[1][t] + sstat[2][t] + sstat[3][t];
}

// ---------------------------------------------------------------------------
// bn1_params: reduce per-block partials then finalize BN1 scale/shift.
// ---------------------------------------------------------------------------
__global__ __launch_bounds__(1024) void bn1_params_kernel(
    const float* __restrict__ partials, int P,
    const float* __restrict__ g1, const float* __restrict__ be1,
    float* __restrict__ scsh) {
  __shared__ float red[32][33];
  __shared__ float tot[32];
  int t = threadIdx.x;
  int ch = t & 31, seg = t >> 5;
  float s = 0.f;
  for (int b = seg; b < P; b += 32) s += partials[b * 32 + ch];
  red[seg][ch] = s;
  __syncthreads();
  if (t < 32) {
    float v = 0.f;
    for (int k = 0; k < 32; k++) v += red[k][t];
    tot[t] = v;
  }
  __syncthreads();
  if (t < FH) {
    float m = tot[t] * (1.0f / NN);
    float var = tot[FH + t] * (1.0f / NN) - m * m;
    float sc = g1[t] * rsqrtf(var + EPS);
    scsh[t] = sc;
    scsh[FH + t] = be1[t] - m * sc;
  }
}

// ---------------------------------------------------------------------------
// proj2: hb = bn1(h1) on the fly; p2b = bf16(hb @ W2l.T), r2 = f32(hb @ W2r.T).
// ---------------------------------------------------------------------------
__global__ __launch_bounds__(256) void proj2_kernel(
    const float* __restrict__ h1, const float* __restrict__ scsh,
    const float* __restrict__ W2l, const float* __restrict__ W2r,
    unsigned short* __restrict__ p2b, float* __restrict__ r2) {
  __shared__ float sWl[FH * FH];
  __shared__ float sWr[FH * FH];
  __shared__ float sc[FH], sh[FH];
  int t = threadIdx.x;
  if (t < FH * FH) {
    sWl[t] = W2l[t];
    sWr[t] = W2r[t];
  }
  if (t < FH) {
    sc[t] = scsh[t];
    sh[t] = scsh[FH + t];
  }
  __syncthreads();

  int n = blockIdx.x * 256 + t;
  if (n >= NN) return;
  float hb[FH];
#pragma unroll
  for (int k = 0; k < FH; k += 4) {
    float4 v = *(const float4*)(h1 + n * FH + k);
    hb[k]     = v.x * sc[k]     + sh[k];
    hb[k + 1] = v.y * sc[k + 1] + sh[k + 1];
    hb[k + 2] = v.z * sc[k + 2] + sh[k + 2];
    hb[k + 3] = v.w * sc[k + 3] + sh[k + 3];
  }
  float po[FH], ro[FH];
#pragma unroll
  for (int j = 0; j < FH; j++) {
    float a = 0.f, b = 0.f;
#pragma unroll
    for (int k = 0; k < FH; k++) {
      a += sWl[j * FH + k] * hb[k];
      b += sWr[j * FH + k] * hb[k];
    }
    po[j] = a; ro[j] = b;
  }
  unsigned pk[8];
#pragma unroll
  for (int j = 0; j < 8; j++)
    pk[j] = (unsigned)f2bf(po[2 * j]) | ((unsigned)f2bf(po[2 * j + 1]) << 16);
  uint4* pd = (uint4*)(p2b + n * FH);
  pd[0] = make_uint4(pk[0], pk[1], pk[2], pk[3]);
  pd[1] = make_uint4(pk[4], pk[5], pk[6], pk[7]);
#pragma unroll
  for (int j = 0; j < FH; j += 4)
    *(float4*)(r2 + n * FH + j) = make_float4(ro[j], ro[j + 1], ro[j + 2], ro[j + 3]);
}

// ---------------------------------------------------------------------------
// sageC2: register-accumulating conv2 + graph mean-pool. batch sorted ->
// wave-uniform fast path; ub>=0 guard excludes padding waves (r2 OOB bug).
// ---------------------------------------------------------------------------
__global__ __launch_bounds__(256) void sageC2_kernel(
    const unsigned int* __restrict__ binned2, const int* __restrict__ nstart,
    const unsigned short* __restrict__ p2b, const float* __restrict__ r2,
    const float* __restrict__ b2, const int* __restrict__ batch,
    float* __restrict__ gsum) {
  int t = threadIdx.x;
  int gid = blockIdx.x * 256 + t;
  int n = gid >> 2;
  int c = gid & 3;
  const uint2* pb = (const uint2*)p2b;

  float h[4] = {0.f, 0.f, 0.f, 0.f};
  int b = -1;
  if (n < NN) {
    int beg = nstart[n], end = nstart[n + 1];
    float ivd = 1.0f / (float)max(end - beg, 1);
    float a0 = 0.f, a1 = 0.f, a2 = 0.f, a3 = 0.f;
    int e = beg;
    for (; e + 1 < end; e += 2) {
      int s0 = binned2[e], s1 = binned2[e + 1];
      uint2 g0 = pb[s0 * 4 + c];
      uint2 g1 = pb[s1 * 4 + c];
      a0 += __uint_as_float((g0.x & 0xFFFFu) << 16) + __uint_as_float((g1.x & 0xFFFFu) << 16);
      a1 += __uint_as_float(g0.x & 0xFFFF0000u) + __uint_as_float(g1.x & 0xFFFF0000u);
      a2 += __uint_as_float((g0.y & 0xFFFFu) << 16) + __uint_as_float((g1.y & 0xFFFFu) << 16);
      a3 += __uint_as_float(g0.y & 0xFFFF0000u) + __uint_as_float(g1.y & 0xFFFF0000u);
    }
    if (e < end) {
      uint2 g0 = pb[binned2[e] * 4 + c];
      a0 += __uint_as_float((g0.x & 0xFFFFu) << 16);
      a1 += __uint_as_float(g0.x & 0xFFFF0000u);
      a2 += __uint_as_float((g0.y & 0xFFFFu) << 16);
      a3 += __uint_as_float(g0.y & 0xFFFF0000u);
    }
    float4 rv = *(const float4*)(r2 + n * FH + c * 4);
    float4 bv = *(const float4*)(b2 + c * 4);
    h[0] = fmaxf(a0 * ivd + rv.x + bv.x, 0.f);
    h[1] = fmaxf(a1 * ivd + rv.y + bv.y, 0.f);
    h[2] = fmaxf(a2 * ivd + rv.z + bv.z, 0.f);
    h[3] = fmaxf(a3 * ivd + rv.w + bv.w, 0.f);
    b = batch[n];
  }

  int ub = __shfl(b, 0);
  bool uniform = __all(b == ub);
  if (uniform && ub >= 0) {
#pragma unroll
    for (int off = 4; off < 64; off <<= 1)
#pragma unroll
      for (int j = 0; j < 4; j++) h[j] += __shfl_xor(h[j], off);
    if ((t & 63) < 4) {
#pragma unroll
      for (int j = 0; j < 4; j++) atomicAdd(gsum + ub * FH + c * 4 + j, h[j]);
    }
  } else if (n < NN) {
#pragma unroll
    for (int j = 0; j < 4; j++) atomicAdd(gsum + b * FH + c * 4 + j, h[j]);
  }
}

// ---------------------------------------------------------------------------
// head: whole D2RL dense head in one block; per-graph counts via binary
// search on sorted batch.
// ---------------------------------------------------------------------------
__global__ __launch_bounds__(256) void head_kernel(
    const float* __restrict__ gsum, const int* __restrict__ batch,
    const float* __restrict__ gn1, const float* __restrict__ bn1,
    const float* __restrict__ Wl1, const float* __restrict__ bl1,
    const float* __restrict__ gn2, const float* __restrict__ bn2,
    const float* __restrict__ Wl2, const float* __restrict__ bl2,
    const float* __restrict__ gn3, const float* __restrict__ bn3,
    const float* __restrict__ Wl3, const float* __restrict__ bl3,
    const float* __restrict__ Wout, const float* __restrict__ bout,
    float* __restrict__ out) {
  __shared__ float sxe[FH * NG];
  __shared__ float sz[FH * NG];
  __shared__ float sz2[FH * NG];
  __shared__ float sc1[FH], sh1[FH], sc2[2 * FH], sh2[2 * FH], sc3[2 * FH], sh3[2 * FH];

  int g = threadIdx.x;
  int lo = 0, hi = NN;
  while (lo < hi) { int mid = (lo + hi) >> 1; if (batch[mid] < g) lo = mid + 1; else hi = mid; }
  int lo2 = lo, hi2 = NN;
  while (lo2 < hi2) { int mid = (lo2 + hi2) >> 1; if (batch[mid] < g + 1) lo2 = mid + 1; else hi2 = mid; }
  float cnt = fmaxf((float)(lo2 - lo), 1.0f);

  float xe[FH];
#pragma unroll
  for (int c = 0; c < FH; c++) {
    xe[c] = gsum[g * FH + c] / cnt;
    sxe[c * NG + g] = xe[c];
  }
  __syncthreads();

  if (g < FH) {
    float s = 0.f, q = 0.f;
    for (int i = 0; i < NG; i++) {
      float v = sxe[g * NG + i];
      s += v; q += v * v;
    }
    float m = s * (1.0f / NG);
    float var = q * (1.0f / NG) - m * m;
    float sc = gn1[g] * rsqrtf(var + EPS);
    sc1[g] = sc;
    sh1[g] = bn1[g] - m * sc;
  }
  __syncthreads();

  float z1[FH];
  {
    float xb[FH];
#pragma unroll
    for (int k = 0; k < FH; k++) xb[k] = xe[k] * sc1[k] + sh1[k];
#pragma unroll
    for (int j = 0; j < FH; j++) {
      float acc = bl1[j];
#pragma unroll
      for (int k = 0; k < FH; k++) acc += Wl1[j * FH + k] * xb[k];
      z1[j] = fmaxf(acc, 0.f);
      sz[j * NG + g] = z1[j];
    }
  }
  __syncthreads();

  if (g < 2 * FH) {
    const float* col = (g < FH) ? (sz + g * NG) : (sxe + (g - FH) * NG);
    float s = 0.f, q = 0.f;
    for (int i = 0; i < NG; i++) {
      float v = col[i];
      s += v; q += v * v;
    }
    float m = s * (1.0f / NG);
    float var = q * (1.0f / NG) - m * m;
    float sc = gn2[g] * rsqrtf(var + EPS);
    sc2[g] = sc;
    sh2[g] = bn2[g] - m * sc;
  }
  __syncthreads();

  float z2[FH];
  {
    float cat[2 * FH];
#pragma unroll
    for (int k = 0; k < FH; k++) {
      cat[k] = z1[k] * sc2[k] + sh2[k];
      cat[FH + k] = xe[k] * sc2[FH + k] + sh2[FH + k];
    }
#pragma unroll
    for (int j = 0; j < FH; j++) {
      float acc = bl2[j];
#pragma unroll
      for (int k = 0; k < 2 * FH; k++) acc += Wl2[j * 2 * FH + k] * cat[k];
      z2[j] = fmaxf(acc, 0.f);
      sz2[j * NG + g] = z2[j];
    }
  }
  __syncthreads();

  if (g < 2 * FH) {
    const float* col = (g < FH) ? (sz2 + g * NG) : (sxe + (g - FH) * NG);
    float s = 0.f, q = 0.f;
    for (int i = 0; i < NG; i++) {
      float v = col[i];
      s += v; q += v * v;
    }
    float m = s * (1.0f / NG);
    float var = q * (1.0f / NG) - m * m;
    float sc = gn3[g] * rsqrtf(var + EPS);
    sc3[g] = sc;
    sh3[g] = bn3[g] - m * sc;
  }
  __syncthreads();

  {
    float cat[2 * FH];
#pragma unroll
    for (int k = 0; k < FH; k++) {
      cat[k] = z2[k] * sc3[k] + sh3[k];
      cat[FH + k] = xe[k] * sc3[FH + k] + sh3[FH + k];
    }
    float o = bout[0];
#pragma unroll
    for (int j = 0; j < FH; j++) {
      float acc = bl3[j];
#pragma unroll
      for (int k = 0; k < 2 * FH; k++) acc += Wl3[j * 2 * FH + k] * cat[k];
      o += Wout[j] * fmaxf(acc, 0.f);
    }
    out[g] = o;
  }
}

// ---------------------------------------------------------------------------
extern "C" void kernel_launch(void* const* d_in, const int* in_sizes, int n_in,
                              void* d_out, int out_size, void* d_ws, size_t ws_size,
                              hipStream_t stream) {
  const float* x    = (const float*)d_in[0];
  const int*   ei   = (const int*)d_in[1];
  const int*   batch= (const int*)d_in[2];
  const float* W1l  = (const float*)d_in[3];
  const float* W1r  = (const float*)d_in[4];
  const float* b1   = (const float*)d_in[5];
  const float* g1   = (const float*)d_in[6];
  const float* be1  = (const float*)d_in[7];
  const float* W2l  = (const float*)d_in[8];
  const float* W2r  = (const float*)d_in[9];
  const float* b2   = (const float*)d_in[10];
  const float* gn1  = (const float*)d_in[11];
  const float* bn1  = (const float*)d_in[12];
  const float* Wl1  = (const float*)d_in[13];
  const float* bl1  = (const float*)d_in[14];
  const float* gn2  = (const float*)d_in[15];
  const float* bn2  = (const float*)d_in[16];
  const float* Wl2  = (const float*)d_in[17];
  const float* bl2  = (const float*)d_in[18];
  const float* gn3  = (const float*)d_in[19];
  const float* bn3  = (const float*)d_in[20];
  const float* Wl3  = (const float*)d_in[21];
  const float* bl3  = (const float*)d_in[22];
  const float* Wout = (const float*)d_in[23];
  const float* bout = (const float*)d_in[24];

  int* wi = (int*)d_ws;
  size_t off = 0;
  float* gsum        = (float*)(wi + off); off += NG * FH;          // zeroed
  int*   cntmat      = wi + off;           off += (size_t)NBUK * NAB;
  int*   bucket_cnt  = wi + off;           off += NBUK;
  int*   bucket_base = wi + off;           off += NBUK + 1;
  unsigned int* binned  = (unsigned int*)(wi + off); off += NE;
  unsigned int* binned2 = (unsigned int*)(wi + off); off += NE;
  int*   nstart      = wi + off;           off += NN + 1;
  float* partials    = (float*)(wi + off); off += (size_t)NBUK * 32;
  float* scsh        = (float*)(wi + off); off += 32;
  off = (off + 3) & ~(size_t)3;                                     // 16B align
  unsigned short* y1b = (unsigned short*)(wi + off); off += (size_t)NN * FH / 2;
  float* r1          = (float*)(wi + off); off += (size_t)NN * FH;
  float* h1          = (float*)(wi + off); off += (size_t)NN * FH;
  unsigned short* p2b = y1b;   // reuse
  float* r2           = r1;    // reuse

  hipMemsetAsync(d_ws, 0, (size_t)NG * FH * sizeof(float), stream);

  int nodeBlocks = (NN + 255) / 256;
  int sageBlocks = (NN * 4 + 255) / 256;  // 1563

  countA_kernel<<<NAB, 256, 0, stream>>>(ei, cntmat);
  bscan1_kernel<<<(NBUK + 255) / 256, 256, 0, stream>>>(cntmat, bucket_cnt);
  bscan2_kernel<<<1, 1024, 0, stream>>>(bucket_cnt, bucket_base);
  bscan3_kernel<<<(NBUK + 255) / 256, 256, 0, stream>>>(cntmat, bucket_base);
  binB_kernel<<<NAB, 256, 0, stream>>>(ei, cntmat, binned);
  binC_kernel<<<NBUK, 256, 0, stream>>>(binned, bucket_base, nstart, binned2);
  proj1_kernel<<<nodeBlocks, 256, 0, stream>>>(x, W1l, W1r, y1b, r1);
  sageC1_kernel<<<sageBlocks, 256, 0, stream>>>(binned2, nstart, y1b, r1, b1, h1, partials);
  bn1_params_kernel<<<1, 1024, 0, stream>>>(partials, sageBlocks, g1, be1, scsh);
  proj2_kernel<<<nodeBlocks, 256, 0, stream>>>(h1, scsh, W2l, W2r, p2b, r2);
  sageC2_kernel<<<sageBlocks, 256, 0, stream>>>(binned2, nstart, p2b, r2, b2, batch, gsum);
  head_kernel<<<1, 256, 0, stream>>>(gsum, batch, gn1, bn1, Wl1, bl1,
                                     gn2, bn2, Wl2, bl2, gn3, bn3, Wl3, bl3,
                                     Wout, bout, (float*)d_out);
}